// Round 1
// baseline (5662.028 us; speedup 1.0000x reference)
//
#include <hip/hip_runtime.h>
#include <math.h>

// ---------------------------------------------------------------------------
// SpatialAttentionModel on MI355X.
// Restructured: (1) init h0/c0, (2) precompute LSTM input projections,
// (3) ONE sequential LSTM chain (497 steps) recording h at frame boundaries,
// (4) batched attention (Vp GEMM + z + scrambled softmax + weighted sum),
// (5) batched 3-layer MLP.
// BS=64, T=32, GRID=36, FEAT=256, HID=256, PROJ=128, NCLS=6, MLP_IN=512.
// ---------------------------------------------------------------------------

typedef _Float16 h2_t __attribute__((ext_vector_type(2)));

#if __has_builtin(__builtin_amdgcn_fdot2)
#define HAVE_FDOT2 1
#else
#define HAVE_FDOT2 0
#endif

__device__ __forceinline__ float dot2(unsigned w, unsigned h, float acc) {
#if HAVE_FDOT2
  return __builtin_amdgcn_fdot2(__builtin_bit_cast(h2_t, w),
                                __builtin_bit_cast(h2_t, h), acc, false);
#else
  h2_t a = __builtin_bit_cast(h2_t, w);
  h2_t b = __builtin_bit_cast(h2_t, h);
  return acc + (float)a[0] * (float)b[0] + (float)a[1] * (float)b[1];
#endif
}

__device__ __forceinline__ unsigned pack2(float a, float b) {
  h2_t p;
  p[0] = (_Float16)a;
  p[1] = (_Float16)b;
  return __builtin_bit_cast(unsigned, p);
}

__device__ __forceinline__ float sigmoid_f(float x) {
  return __builtin_amdgcn_rcpf(1.f + __expf(-x));
}
__device__ __forceinline__ float tanh_f(float x) {
  return 1.f - 2.f * __builtin_amdgcn_rcpf(1.f + __expf(2.f * x));
}

// ---------------------------------------------------------------------------
// Pack Whh into the LSTM kernel's two layouts:
//  wv_pack[m][tau] (m<208, tau<512): VGPR-resident pairs 24..127 of rows tau
//  (m<104) and tau+512 (m>=104).
//  wlds_pack[row][p] (p<24): pairs 0..23 of every row (re-read from LDS).
__global__ void k_pack_wv(const float* __restrict__ Whh,
                          unsigned* __restrict__ wv_pack,
                          unsigned* __restrict__ wlds_pack) {
  const int idx = blockIdx.x * 256 + threadIdx.x;  // < 131072
  if (idx < 106496) {
    const int m = idx >> 9, tau = idx & 511;
    const int row = (m < 104) ? tau : tau + 512;
    const int pair = (m < 104) ? (24 + m) : (24 + m - 104);
    wv_pack[idx] = pack2(Whh[row * 256 + 2 * pair], Whh[row * 256 + 2 * pair + 1]);
  } else {
    const int j = idx - 106496;  // < 24576
    const int row = j / 24, pair = j - row * 24;
    wlds_pack[j] = pack2(Whh[row * 256 + 2 * pair], Whh[row * 256 + 2 * pair + 1]);
  }
}

// Generic f32 -> packed-f16-pair converter (contiguous rows, even cols).
__global__ void k_packh2(const float* __restrict__ src,
                         unsigned* __restrict__ dst, int n) {
  const int i = blockIdx.x * 256 + threadIdx.x;
  if (i < n) dst[i] = pack2(src[2 * i], src[2 * i + 1]);
}

// xg[t][b][j] = gaze[b,t,:]·Wih[j,:] + bih[j] + bhh[j],  t in [0,31)
__global__ void k_xg(const float* __restrict__ gaze,
                     const float* __restrict__ Wih,
                     const float* __restrict__ bih,
                     const float* __restrict__ bhh,
                     float* __restrict__ xg) {
  const int idx = blockIdx.x * 256 + threadIdx.x;
  if (idx >= 31 * 64 * 1024) return;
  const int j = idx & 1023;
  const int b = (idx >> 10) & 63;
  const int t = idx >> 16;
  const float* gz = gaze + (b * 32 + t) * 3;
  xg[idx] = gz[0] * Wih[j * 3 + 0] + gz[1] * Wih[j * 3 + 1] +
            gz[2] * Wih[j * 3 + 2] + bih[j] + bhh[j];
}

// h0/c0: h = tanh(tanh( tanh(mg@Wh1.T+bh1) @ Wh2.T + bh2 )), same for c.
__global__ void k_init(const float* __restrict__ gaze,
                       const float* __restrict__ Wh1, const float* __restrict__ bh1,
                       const float* __restrict__ Wh2, const float* __restrict__ bh2,
                       const float* __restrict__ Wc1, const float* __restrict__ bc1,
                       const float* __restrict__ Wc2, const float* __restrict__ bc2,
                       float* __restrict__ HH, float* __restrict__ c0) {
  const int b = blockIdx.x;
  const int tid = threadIdx.x;  // 256
  __shared__ float mg[3];
  __shared__ float t1h[256], t1c[256];
  if (tid < 3) {
    float s = 0.f;
    for (int t = 0; t < 32; t++) s += gaze[(b * 32 + t) * 3 + tid];
    mg[tid] = s * (1.f / 32.f);
  }
  __syncthreads();
  {
    float a = mg[0] * Wh1[tid * 3 + 0] + mg[1] * Wh1[tid * 3 + 1] +
              mg[2] * Wh1[tid * 3 + 2] + bh1[tid];
    t1h[tid] = tanhf(a);
    float c = mg[0] * Wc1[tid * 3 + 0] + mg[1] * Wc1[tid * 3 + 1] +
              mg[2] * Wc1[tid * 3 + 2] + bc1[tid];
    t1c[tid] = tanhf(c);
  }
  __syncthreads();
  float s1 = bh2[tid], s2 = bc2[tid];
  for (int k = 0; k < 256; k++) {
    s1 += t1h[k] * Wh2[tid * 256 + k];
    s2 += t1c[k] * Wc2[tid * 256 + k];
  }
  HH[b * 256 + tid] = tanhf(tanhf(s1));  // HH[0][b][k]
  c0[b * 256 + tid] = tanhf(tanhf(s2));
}

// ---------------------------------------------------------------------------
// The sequential LSTM chain. One block per batch element. 512 threads;
// thread tau owns gate rows tau and tau+512. f16 weights: pairs 24..127 in
// VGPRs (208 dwords), pairs 0..23 in LDS (stride-28 rows). h broadcast from
// LDS as packed-f16 uint4. Records h at the 32 frame boundaries into HH[1..32].
__global__ __launch_bounds__(512, 2) void k_lstm(
    const float* __restrict__ xg, const unsigned* __restrict__ wv_pack,
    const unsigned* __restrict__ wlds_pack, const float* __restrict__ c0,
    float* __restrict__ HH) {
  const int b = blockIdx.x;
  const int tid = threadIdx.x;
  __shared__ __align__(16) unsigned wlds[1024 * 28];
  __shared__ float actl[1024];
  __shared__ float hfl[256];
  __shared__ __align__(16) unsigned h2l[128];

  for (int i = tid; i < 1024 * 24; i += 512) {
    const int row = i / 24, p = i - row * 24;
    wlds[row * 28 + p] = wlds_pack[i];
  }
  unsigned wv[208];
#pragma unroll
  for (int m = 0; m < 208; m++) wv[m] = wv_pack[m * 512 + tid];

  float cst = (tid < 256) ? c0[b * 256 + tid] : 0.f;
  if (tid < 128)
    h2l[tid] = pack2(HH[b * 256 + 2 * tid], HH[b * 256 + 2 * tid + 1]);
  __syncthreads();

  const unsigned* wA = &wlds[tid * 28];
  const unsigned* wB = &wlds[(tid + 512) * 28];
  float hval = 0.f;

  for (int frame = 0; frame < 32; frame++) {
    const int L = frame ? frame : 1;
    for (int t = 0; t < L; t++) {
      const float* xgt = xg + (t * 64 + b) * 1024;
      const float xga = xgt[tid];
      const float xgb = xgt[tid + 512];
      float ga0 = 0.f, ga1 = 0.f, gb0 = 0.f, gb1 = 0.f;
#pragma unroll
      for (int q = 0; q < 6; q++) {
        const uint4 h4 = *(const uint4*)&h2l[4 * q];
        const uint4 a4 = *(const uint4*)&wA[4 * q];
        const uint4 b4 = *(const uint4*)&wB[4 * q];
        if ((q & 1) == 0) {
          ga0 = dot2(a4.x, h4.x, ga0); gb0 = dot2(b4.x, h4.x, gb0);
          ga0 = dot2(a4.y, h4.y, ga0); gb0 = dot2(b4.y, h4.y, gb0);
          ga0 = dot2(a4.z, h4.z, ga0); gb0 = dot2(b4.z, h4.z, gb0);
          ga0 = dot2(a4.w, h4.w, ga0); gb0 = dot2(b4.w, h4.w, gb0);
        } else {
          ga1 = dot2(a4.x, h4.x, ga1); gb1 = dot2(b4.x, h4.x, gb1);
          ga1 = dot2(a4.y, h4.y, ga1); gb1 = dot2(b4.y, h4.y, gb1);
          ga1 = dot2(a4.z, h4.z, ga1); gb1 = dot2(b4.z, h4.z, gb1);
          ga1 = dot2(a4.w, h4.w, ga1); gb1 = dot2(b4.w, h4.w, gb1);
        }
      }
#pragma unroll
      for (int q = 0; q < 26; q++) {
        const uint4 h4 = *(const uint4*)&h2l[24 + 4 * q];
        if ((q & 1) == 0) {
          ga0 = dot2(wv[4 * q + 0], h4.x, ga0); gb0 = dot2(wv[104 + 4 * q + 0], h4.x, gb0);
          ga0 = dot2(wv[4 * q + 1], h4.y, ga0); gb0 = dot2(wv[104 + 4 * q + 1], h4.y, gb0);
          ga0 = dot2(wv[4 * q + 2], h4.z, ga0); gb0 = dot2(wv[104 + 4 * q + 2], h4.z, gb0);
          ga0 = dot2(wv[4 * q + 3], h4.w, ga0); gb0 = dot2(wv[104 + 4 * q + 3], h4.w, gb0);
        } else {
          ga1 = dot2(wv[4 * q + 0], h4.x, ga1); gb1 = dot2(wv[104 + 4 * q + 0], h4.x, gb1);
          ga1 = dot2(wv[4 * q + 1], h4.y, ga1); gb1 = dot2(wv[104 + 4 * q + 1], h4.y, gb1);
          ga1 = dot2(wv[4 * q + 2], h4.z, ga1); gb1 = dot2(wv[104 + 4 * q + 2], h4.z, gb1);
          ga1 = dot2(wv[4 * q + 3], h4.w, ga1); gb1 = dot2(wv[104 + 4 * q + 3], h4.w, gb1);
        }
      }
      const float ga = ga0 + ga1 + xga;  // row tid     (i-gate or f-gate)
      const float gb = gb0 + gb1 + xgb;  // row tid+512 (g-gate or o-gate)
      const float acta = sigmoid_f(ga);
      const float actb = (tid < 256) ? tanh_f(gb) : sigmoid_f(gb);
      actl[tid] = acta;
      actl[tid + 512] = actb;
      __syncthreads();  // B1: MAC reads of h2l done; acts visible
      if (tid < 256) {
        const float i_ = actl[tid];
        const float f_ = actl[256 + tid];
        const float g_ = actl[512 + tid];
        const float o_ = actl[768 + tid];
        cst = f_ * cst + i_ * g_;
        hval = o_ * tanh_f(cst);
        hfl[tid] = hval;
      }
      __syncthreads();  // B2: hfl visible
      if (tid < 128) h2l[tid] = pack2(hfl[2 * tid], hfl[2 * tid + 1]);
      __syncthreads();  // B3: h2l ready for next step
    }
    if (tid < 256) HH[((frame + 1) * 64 + b) * 256 + tid] = hval;
  }
}

// Hl[i][b][p] = HH[i][b]·W_lh[p] + b_lh[p]. One block per frame.
__global__ void k_hl(const float* __restrict__ HH,
                     const unsigned* __restrict__ wlh_h2,
                     const float* __restrict__ blh, float* __restrict__ Hl) {
  const int i = blockIdx.x;
  const int tid = threadIdx.x;  // 256
  __shared__ __align__(16) unsigned Ah[64 * 132];
  __shared__ __align__(16) unsigned Bh[128 * 132];
  for (int idx = tid; idx < 64 * 128; idx += 256) {
    const int r = idx >> 7, kp = idx & 127;
    const float* s = HH + ((size_t)(i * 64 + r)) * 256 + 2 * kp;
    Ah[r * 132 + kp] = pack2(s[0], s[1]);
  }
  for (int idx = tid; idx < 128 * 128; idx += 256) {
    const int o = idx >> 7, kp = idx & 127;
    Bh[o * 132 + kp] = wlh_h2[o * 128 + kp];
  }
  __syncthreads();
  const int ry = tid >> 4, px = tid & 15;
  float acc[4][8];
#pragma unroll
  for (int k = 0; k < 4; k++)
#pragma unroll
    for (int j = 0; j < 8; j++) acc[k][j] = 0.f;
  for (int kb = 0; kb < 32; kb++) {
    uint4 a4[4], b4[8];
#pragma unroll
    for (int k = 0; k < 4; k++) a4[k] = *(const uint4*)&Ah[(16 * k + ry) * 132 + 4 * kb];
#pragma unroll
    for (int j = 0; j < 8; j++) b4[j] = *(const uint4*)&Bh[(16 * j + px) * 132 + 4 * kb];
#pragma unroll
    for (int k = 0; k < 4; k++)
#pragma unroll
      for (int j = 0; j < 8; j++) {
        acc[k][j] = dot2(a4[k].x, b4[j].x, acc[k][j]);
        acc[k][j] = dot2(a4[k].y, b4[j].y, acc[k][j]);
        acc[k][j] = dot2(a4[k].z, b4[j].z, acc[k][j]);
        acc[k][j] = dot2(a4[k].w, b4[j].w, acc[k][j]);
      }
  }
#pragma unroll
  for (int k = 0; k < 4; k++)
#pragma unroll
    for (int j = 0; j < 8; j++)
      Hl[(i * 64 + 16 * k + ry) * 128 + 16 * j + px] = acc[k][j] + blh[16 * j + px];
}

// Fused Vp GEMM + z. Rows = flattened (b,g) within frame i (2304 rows, tiles
// of 128). z[b,g] = sum_p w[p]*tanh(Hl[b,p] + Vp[b,g,p]).
__global__ void k_att_z(const float* __restrict__ cnn,
                        const unsigned* __restrict__ wcn_h2,
                        const float* __restrict__ bcn,
                        const float* __restrict__ Hl,
                        const float* __restrict__ wwt,
                        float* __restrict__ zbuf) {
  const int bid = blockIdx.x;  // 576 = 32 frames * 18 row tiles
  const int i = bid / 18, rt = bid - 18 * i;
  const int tid = threadIdx.x;  // 256
  const int r0 = rt * 128;
  __shared__ __align__(16) unsigned As[128 * 132];
  __shared__ __align__(16) unsigned Bs[128 * 132];
  __shared__ float zpart[128 * 16];
  __shared__ float Hls[5 * 128];
  __shared__ float wws[128];
  __shared__ float bcs[128];

  for (int idx = tid; idx < 128 * 128; idx += 256) {
    const int r = idx >> 7, kp = idx & 127;
    const int R = r0 + r;
    const int b = R / 36, g = R - b * 36;
    const float* src = cnn + (((size_t)b * 32 + i) * 36 + g) * 256 + 2 * kp;
    As[r * 132 + kp] = pack2(src[0], src[1]);
  }
  for (int idx = tid; idx < 128 * 128; idx += 256) {
    const int o = idx >> 7, kp = idx & 127;
    Bs[o * 132 + kp] = wcn_h2[o * 128 + kp];
  }
  const int bmin = r0 / 36;
  for (int idx = tid; idx < 5 * 128; idx += 256) {
    const int bb = bmin + (idx >> 7);
    if (bb < 64) Hls[idx] = Hl[(i * 64 + bb) * 128 + (idx & 127)];
  }
  if (tid < 128) {
    wws[tid] = wwt[tid];
    bcs[tid] = bcn[tid];
  }
  __syncthreads();

  const int ry = tid >> 4, px = tid & 15;
  float acc[8][8];
#pragma unroll
  for (int k = 0; k < 8; k++)
#pragma unroll
    for (int j = 0; j < 8; j++) acc[k][j] = bcs[16 * j + px];
  for (int kb = 0; kb < 32; kb++) {
    uint4 a4[8], b4[8];
#pragma unroll
    for (int k = 0; k < 8; k++) a4[k] = *(const uint4*)&As[(16 * k + ry) * 132 + 4 * kb];
#pragma unroll
    for (int j = 0; j < 8; j++) b4[j] = *(const uint4*)&Bs[(16 * j + px) * 132 + 4 * kb];
#pragma unroll
    for (int k = 0; k < 8; k++)
#pragma unroll
      for (int j = 0; j < 8; j++) {
        acc[k][j] = dot2(a4[k].x, b4[j].x, acc[k][j]);
        acc[k][j] = dot2(a4[k].y, b4[j].y, acc[k][j]);
        acc[k][j] = dot2(a4[k].z, b4[j].z, acc[k][j]);
        acc[k][j] = dot2(a4[k].w, b4[j].w, acc[k][j]);
      }
  }
#pragma unroll
  for (int k = 0; k < 8; k++) {
    const int r = 16 * k + ry;
    const int R = r0 + r;
    const int b = R / 36;
    const float* HlRow = &Hls[(b - bmin) * 128];
    float zp = 0.f;
#pragma unroll
    for (int j = 0; j < 8; j++) {
      const int po = 16 * j + px;
      zp += wws[po] * tanh_f(HlRow[po] + acc[k][j]);
    }
    zpart[r * 16 + px] = zp;
  }
  __syncthreads();
  if (tid < 128) {
    float z = 0.f;
#pragma unroll
    for (int x = 0; x < 16; x++) z += zpart[tid * 16 + x];
    const int R = r0 + tid;
    const int b = R / 36, g = R - b * 36;
    zbuf[(i * 64 + b) * 36 + g] = z;
  }
}

// Scrambled softmax + weighted V sum; builds fc = [spatial_feat | h_next].
__global__ void k_att_sf(const float* __restrict__ cnn,
                         const float* __restrict__ zbuf,
                         const float* __restrict__ HH,
                         float* __restrict__ fc) {
  const int bid = blockIdx.x;  // 2048 = i*64 + b
  const int i = bid >> 6, b = bid & 63;
  const int tid = threadIdx.x;  // 256
  __shared__ float zl[36];
  __shared__ float el[40];
  __shared__ float red[1];
  if (tid < 36) {
    const int idx = b * 36 + tid;  // scramble: z.T.reshape(64,36)
    zl[tid] = zbuf[(i * 64 + (idx & 63)) * 36 + (idx >> 6)];
  }
  __syncthreads();
  if (tid == 0) {
    float m = zl[0];
    for (int g = 1; g < 36; g++) m = fmaxf(m, zl[g]);
    float s = 0.f;
    for (int g = 0; g < 36; g++) {
      const float e = __expf(zl[g] - m);
      el[g] = e;
      s += e;
    }
    red[0] = 1.f / s;
  }
  __syncthreads();
  const float inv = red[0];
  float accv = 0.f;
  const float* Vb = cnn + (((size_t)b * 32 + i) * 36) * 256 + tid;
#pragma unroll 4
  for (int g = 0; g < 36; g++) accv += el[g] * Vb[g * 256];
  fc[(size_t)bid * 512 + tid] = accv * inv;
  fc[(size_t)bid * 512 + 256 + tid] = HH[((i + 1) * 64 + b) * 256 + tid];
}

// MLP layers 1/2: (2048,512)@(512,512)+b, output packed f16 pairs.
template <int SRCMODE>  // 0: f32 src (fc), 1: packed-h2 src
__global__ void k_mlp(const void* __restrict__ src,
                      const unsigned* __restrict__ wh2,
                      const float* __restrict__ bias,
                      unsigned* __restrict__ dst) {
  const int bid = blockIdx.x;  // 128 = 32 n-tiles * 4 o-tiles
  const int nb = bid >> 2, ob = bid & 3;
  const int n0 = nb * 64, o0 = ob * 128;
  const int tid = threadIdx.x;
  __shared__ __align__(16) unsigned As[64 * 132];
  __shared__ __align__(16) unsigned Bs[128 * 132];
  const int ry = tid >> 4, px = tid & 15;
  float acc[4][8];
#pragma unroll
  for (int k = 0; k < 4; k++)
#pragma unroll
    for (int m = 0; m < 8; m++)
      acc[k][m] = bias[o0 + 32 * (m >> 1) + 2 * px + (m & 1)];
  for (int kc = 0; kc < 2; kc++) {
    __syncthreads();
    for (int idx = tid; idx < 64 * 128; idx += 256) {
      const int r = idx >> 7, kp = idx & 127;
      if (SRCMODE == 0) {
        const float* s = (const float*)src + ((size_t)(n0 + r)) * 512 + kc * 256 + 2 * kp;
        As[r * 132 + kp] = pack2(s[0], s[1]);
      } else {
        As[r * 132 + kp] = ((const unsigned*)src)[((size_t)(n0 + r)) * 256 + kc * 128 + kp];
      }
    }
    for (int idx = tid; idx < 128 * 128; idx += 256) {
      const int o = idx >> 7, kp = idx & 127;
      Bs[o * 132 + kp] = wh2[((size_t)(o0 + o)) * 256 + kc * 128 + kp];
    }
    __syncthreads();
    for (int kb = 0; kb < 32; kb++) {
      uint4 a4[4], b4[8];
#pragma unroll
      for (int k = 0; k < 4; k++)
        a4[k] = *(const uint4*)&As[(16 * k + ry) * 132 + 4 * kb];
#pragma unroll
      for (int m = 0; m < 8; m++)
        b4[m] = *(const uint4*)&Bs[(32 * (m >> 1) + 2 * px + (m & 1)) * 132 + 4 * kb];
#pragma unroll
      for (int k = 0; k < 4; k++)
#pragma unroll
        for (int m = 0; m < 8; m++) {
          acc[k][m] = dot2(a4[k].x, b4[m].x, acc[k][m]);
          acc[k][m] = dot2(a4[k].y, b4[m].y, acc[k][m]);
          acc[k][m] = dot2(a4[k].z, b4[m].z, acc[k][m]);
          acc[k][m] = dot2(a4[k].w, b4[m].w, acc[k][m]);
        }
    }
  }
#pragma unroll
  for (int k = 0; k < 4; k++) {
    const int n = n0 + 16 * k + ry;
#pragma unroll
    for (int j = 0; j < 4; j++)
      dst[(size_t)n * 256 + (o0 >> 1) + 16 * j + px] =
          pack2(acc[k][2 * j], acc[k][2 * j + 1]);
  }
}

// Final layer: (2048,512) -> 6 classes.
__global__ void k_mlp3(const unsigned* __restrict__ y2h2,
                       const unsigned* __restrict__ wm3h2,
                       const float* __restrict__ bm3,
                       float* __restrict__ out) {
  const int nb = blockIdx.x;  // 32
  const int tid = threadIdx.x;
  __shared__ __align__(16) unsigned Ys[64 * 256];
  __shared__ __align__(16) unsigned Ws[6 * 256];
  for (int idx = tid; idx < 64 * 256; idx += 256)
    Ys[idx] = y2h2[(size_t)nb * 64 * 256 + idx];
  for (int idx = tid; idx < 6 * 256; idx += 256) Ws[idx] = wm3h2[idx];
  __syncthreads();
  for (int u = 0; u < 2; u++) {
    const int idx = tid + u * 256;
    if (idx < 384) {
      const int nl = idx / 6, c = idx - 6 * nl;
      float a0 = 0.f, a1 = 0.f;
#pragma unroll
      for (int kq = 0; kq < 64; kq++) {
        const uint4 y4 = *(const uint4*)&Ys[nl * 256 + 4 * kq];
        const uint4 w4 = *(const uint4*)&Ws[c * 256 + 4 * kq];
        a0 = dot2(y4.x, w4.x, a0);
        a1 = dot2(y4.y, w4.y, a1);
        a0 = dot2(y4.z, w4.z, a0);
        a1 = dot2(y4.w, w4.w, a1);
      }
      out[(size_t)(nb * 64 + nl) * 6 + c] = a0 + a1 + bm3[c];
    }
  }
}

// ---------------------------------------------------------------------------
extern "C" void kernel_launch(void* const* d_in, const int* in_sizes, int n_in,
                              void* d_out, int out_size, void* d_ws,
                              size_t ws_size, hipStream_t stream) {
  (void)in_sizes; (void)n_in; (void)out_size; (void)ws_size;
  const float* cnn  = (const float*)d_in[0];
  const float* gaze = (const float*)d_in[1];
  const float* W_lh = (const float*)d_in[2];
  const float* b_lh = (const float*)d_in[3];
  const float* W_cn = (const float*)d_in[4];
  const float* b_cn = (const float*)d_in[5];
  const float* w_wt = (const float*)d_in[6];
  const float* Wih  = (const float*)d_in[7];
  const float* Whh  = (const float*)d_in[8];
  const float* bih  = (const float*)d_in[9];
  const float* bhh  = (const float*)d_in[10];
  const float* Wh1  = (const float*)d_in[11];
  const float* bh1  = (const float*)d_in[12];
  const float* Wh2  = (const float*)d_in[13];
  const float* bh2  = (const float*)d_in[14];
  const float* Wc1  = (const float*)d_in[15];
  const float* bc1  = (const float*)d_in[16];
  const float* Wc2  = (const float*)d_in[17];
  const float* bc2  = (const float*)d_in[18];
  const float* Wm1  = (const float*)d_in[19];
  const float* bm1  = (const float*)d_in[20];
  const float* Wm2  = (const float*)d_in[21];
  const float* bm2  = (const float*)d_in[22];
  const float* Wm3  = (const float*)d_in[23];
  const float* bm3  = (const float*)d_in[24];
  float* out = (float*)d_out;

  unsigned* W = (unsigned*)d_ws;
  float* Wf = (float*)d_ws;
  // workspace offsets in dwords
  const size_t O_xg  = 0;                    // [31][64][1024] f32
  const size_t O_wv  = 2031616;              // [208][512]     u32
  const size_t O_wl  = O_wv + 106496;        // [1024][24]     u32
  const size_t O_HH  = O_wl + 24576;         // [33][64][256]  f32
  const size_t O_c0  = O_HH + 540672;        // [64][256]      f32
  const size_t O_Hl  = O_c0 + 16384;         // [32][64][128]  f32
  const size_t O_z   = O_Hl + 262144;        // [32][64][36]   f32
  const size_t O_fc  = O_z + 73728;          // [2048][512]    f32
  const size_t O_y1  = O_fc + 1048576;       // [2048][256]    u32 (h2)
  const size_t O_y2  = O_y1 + 524288;        // [2048][256]    u32 (h2)
  const size_t O_wcn = O_y2 + 524288;        // [128][128]     u32
  const size_t O_wlh = O_wcn + 16384;
  const size_t O_wm1 = O_wlh + 16384;        // [512][256]
  const size_t O_wm2 = O_wm1 + 131072;
  const size_t O_wm3 = O_wm2 + 131072;       // [6][256]

  float* xg  = Wf + O_xg;
  float* HH  = Wf + O_HH;
  float* c0f = Wf + O_c0;
  float* Hlf = Wf + O_Hl;
  float* zf  = Wf + O_z;
  float* fcf = Wf + O_fc;

  // --- prepacking (independent) ---
  k_pack_wv<<<512, 256, 0, stream>>>(Whh, W + O_wv, W + O_wl);
  k_packh2<<<64, 256, 0, stream>>>(W_cn, W + O_wcn, 16384);
  k_packh2<<<64, 256, 0, stream>>>(W_lh, W + O_wlh, 16384);
  k_packh2<<<512, 256, 0, stream>>>(Wm1, W + O_wm1, 131072);
  k_packh2<<<512, 256, 0, stream>>>(Wm2, W + O_wm2, 131072);
  k_packh2<<<6, 256, 0, stream>>>(Wm3, W + O_wm3, 1536);
  k_xg<<<7936, 256, 0, stream>>>(gaze, Wih, bih, bhh, xg);
  k_init<<<64, 256, 0, stream>>>(gaze, Wh1, bh1, Wh2, bh2, Wc1, bc1, Wc2, bc2,
                                 HH, c0f);
  // --- the sequential chain ---
  k_lstm<<<64, 512, 0, stream>>>(xg, W + O_wv, W + O_wl, c0f, HH);
  // --- batched attention ---
  k_hl<<<32, 256, 0, stream>>>(HH, W + O_wlh, b_lh, Hlf);
  k_att_z<<<576, 256, 0, stream>>>(cnn, W + O_wcn, b_cn, Hlf, w_wt, zf);
  k_att_sf<<<2048, 256, 0, stream>>>(cnn, zf, HH, fcf);
  // --- batched MLP ---
  k_mlp<0><<<128, 256, 0, stream>>>((const void*)fcf, W + O_wm1, bm1, W + O_y1);
  k_mlp<1><<<128, 256, 0, stream>>>((const void*)(W + O_y1), W + O_wm2, bm2, W + O_y2);
  k_mlp3<<<32, 256, 0, stream>>>(W + O_y2, W + O_wm3, bm3, out);
}

// Round 2
// 5236.473 us; speedup vs baseline: 1.0813x; 1.0813x over previous
//
#include <hip/hip_runtime.h>
#include <math.h>

// ---------------------------------------------------------------------------
// SpatialAttentionModel on MI355X.
// (1) init h0/c0, (2) precompute LSTM input projections, (3) ONE sequential
// LSTM chain (497 steps) recording h at frame boundaries, (4) batched
// attention, (5) batched 3-layer MLP.
// BS=64, T=32, GRID=36, FEAT=256, HID=256, PROJ=128, NCLS=6, MLP_IN=512.
// R2: fix k_lstm VGPR spill (launch_bounds 512 w/o min-waves; 192 weight
// dwords in VGPR + 32 pairs/row in LDS stride-36; 2 barriers/step via
// ds_write_b16 h update).
// ---------------------------------------------------------------------------

typedef _Float16 h2_t __attribute__((ext_vector_type(2)));

#if __has_builtin(__builtin_amdgcn_fdot2)
#define HAVE_FDOT2 1
#else
#define HAVE_FDOT2 0
#endif

__device__ __forceinline__ float dot2(unsigned w, unsigned h, float acc) {
#if HAVE_FDOT2
  return __builtin_amdgcn_fdot2(__builtin_bit_cast(h2_t, w),
                                __builtin_bit_cast(h2_t, h), acc, false);
#else
  h2_t a = __builtin_bit_cast(h2_t, w);
  h2_t b = __builtin_bit_cast(h2_t, h);
  return acc + (float)a[0] * (float)b[0] + (float)a[1] * (float)b[1];
#endif
}

__device__ __forceinline__ unsigned pack2(float a, float b) {
  h2_t p;
  p[0] = (_Float16)a;
  p[1] = (_Float16)b;
  return __builtin_bit_cast(unsigned, p);
}

__device__ __forceinline__ float sigmoid_f(float x) {
  return __builtin_amdgcn_rcpf(1.f + __expf(-x));
}
__device__ __forceinline__ float tanh_f(float x) {
  return 1.f - 2.f * __builtin_amdgcn_rcpf(1.f + __expf(2.f * x));
}

// ---------------------------------------------------------------------------
// Pack Whh into the LSTM kernel's two layouts:
//  wv_pack[m][tau] (m<192, tau<512): VGPR-resident pairs 32..127 of rows tau
//  (m<96) and tau+512 (m>=96).
//  wlds_pack[row][p] (p<32): pairs 0..31 of every row (read from LDS).
__global__ void k_pack_wv(const float* __restrict__ Whh,
                          unsigned* __restrict__ wv_pack,
                          unsigned* __restrict__ wlds_pack) {
  const int idx = blockIdx.x * 256 + threadIdx.x;  // < 131072
  if (idx < 98304) {
    const int m = idx >> 9, tau = idx & 511;
    const int row = (m < 96) ? tau : tau + 512;
    const int pair = 32 + ((m < 96) ? m : m - 96);
    wv_pack[idx] = pack2(Whh[row * 256 + 2 * pair], Whh[row * 256 + 2 * pair + 1]);
  } else {
    const int j = idx - 98304;  // < 32768
    const int row = j >> 5, pair = j & 31;
    wlds_pack[j] = pack2(Whh[row * 256 + 2 * pair], Whh[row * 256 + 2 * pair + 1]);
  }
}

// Generic f32 -> packed-f16-pair converter (contiguous rows, even cols).
__global__ void k_packh2(const float* __restrict__ src,
                         unsigned* __restrict__ dst, int n) {
  const int i = blockIdx.x * 256 + threadIdx.x;
  if (i < n) dst[i] = pack2(src[2 * i], src[2 * i + 1]);
}

// xg[t][b][j] = gaze[b,t,:]·Wih[j,:] + bih[j] + bhh[j],  t in [0,31)
__global__ void k_xg(const float* __restrict__ gaze,
                     const float* __restrict__ Wih,
                     const float* __restrict__ bih,
                     const float* __restrict__ bhh,
                     float* __restrict__ xg) {
  const int idx = blockIdx.x * 256 + threadIdx.x;
  if (idx >= 31 * 64 * 1024) return;
  const int j = idx & 1023;
  const int b = (idx >> 10) & 63;
  const int t = idx >> 16;
  const float* gz = gaze + (b * 32 + t) * 3;
  xg[idx] = gz[0] * Wih[j * 3 + 0] + gz[1] * Wih[j * 3 + 1] +
            gz[2] * Wih[j * 3 + 2] + bih[j] + bhh[j];
}

// h0/c0: h = tanh(tanh( tanh(mg@Wh1.T+bh1) @ Wh2.T + bh2 )), same for c.
__global__ void k_init(const float* __restrict__ gaze,
                       const float* __restrict__ Wh1, const float* __restrict__ bh1,
                       const float* __restrict__ Wh2, const float* __restrict__ bh2,
                       const float* __restrict__ Wc1, const float* __restrict__ bc1,
                       const float* __restrict__ Wc2, const float* __restrict__ bc2,
                       float* __restrict__ HH, float* __restrict__ c0) {
  const int b = blockIdx.x;
  const int tid = threadIdx.x;  // 256
  __shared__ float mg[3];
  __shared__ float t1h[256], t1c[256];
  if (tid < 3) {
    float s = 0.f;
    for (int t = 0; t < 32; t++) s += gaze[(b * 32 + t) * 3 + tid];
    mg[tid] = s * (1.f / 32.f);
  }
  __syncthreads();
  {
    float a = mg[0] * Wh1[tid * 3 + 0] + mg[1] * Wh1[tid * 3 + 1] +
              mg[2] * Wh1[tid * 3 + 2] + bh1[tid];
    t1h[tid] = tanhf(a);
    float c = mg[0] * Wc1[tid * 3 + 0] + mg[1] * Wc1[tid * 3 + 1] +
              mg[2] * Wc1[tid * 3 + 2] + bc1[tid];
    t1c[tid] = tanhf(c);
  }
  __syncthreads();
  float s1 = bh2[tid], s2 = bc2[tid];
  for (int k = 0; k < 256; k++) {
    s1 += t1h[k] * Wh2[tid * 256 + k];
    s2 += t1c[k] * Wc2[tid * 256 + k];
  }
  HH[b * 256 + tid] = tanhf(tanhf(s1));  // HH[0][b][k]
  c0[b * 256 + tid] = tanhf(tanhf(s2));
}

// ---------------------------------------------------------------------------
// The sequential LSTM chain. One block per batch element. 512 threads;
// thread tau owns gate rows tau and tau+512. f16 weights: pairs 32..127 in
// VGPRs (192 dwords), pairs 0..31 in LDS (stride-36 rows). h broadcast from
// LDS as packed-f16 uint4; h written back as ds_write_b16 (no extra buffer).
// Records h at the 32 frame boundaries into HH[1..32].
__global__ __launch_bounds__(512) void k_lstm(
    const float* __restrict__ xg, const unsigned* __restrict__ wv_pack,
    const unsigned* __restrict__ wlds_pack, const float* __restrict__ c0,
    float* __restrict__ HH) {
  const int b = blockIdx.x;
  const int tid = threadIdx.x;
  __shared__ __align__(16) unsigned wlds[1024 * 36];  // 147456 B
  __shared__ float actl[1024];
  __shared__ __align__(16) unsigned h2l[128];

  for (int i = tid; i < 1024 * 32; i += 512) {
    const int row = i >> 5, p = i & 31;
    wlds[row * 36 + p] = wlds_pack[i];
  }
  unsigned wv[192];
#pragma unroll
  for (int m = 0; m < 192; m++) wv[m] = wv_pack[m * 512 + tid];

  float cst = (tid < 256) ? c0[b * 256 + tid] : 0.f;
  if (tid < 256) ((_Float16*)h2l)[tid] = (_Float16)HH[b * 256 + tid];
  __syncthreads();

  const unsigned* wA = &wlds[tid * 36];
  const unsigned* wB = &wlds[(tid + 512) * 36];
  float hval = 0.f;

  for (int frame = 0; frame < 32; frame++) {
    const int L = frame ? frame : 1;
    for (int t = 0; t < L; t++) {
      const float* xgt = xg + (t * 64 + b) * 1024;
      const float xga = xgt[tid];
      const float xgb = xgt[tid + 512];
      float ga0 = 0.f, ga1 = 0.f, gb0 = 0.f, gb1 = 0.f;
#pragma unroll
      for (int q = 0; q < 8; q++) {
        const uint4 h4 = *(const uint4*)&h2l[4 * q];
        const uint4 a4 = *(const uint4*)&wA[4 * q];
        const uint4 b4 = *(const uint4*)&wB[4 * q];
        if ((q & 1) == 0) {
          ga0 = dot2(a4.x, h4.x, ga0); gb0 = dot2(b4.x, h4.x, gb0);
          ga0 = dot2(a4.y, h4.y, ga0); gb0 = dot2(b4.y, h4.y, gb0);
          ga0 = dot2(a4.z, h4.z, ga0); gb0 = dot2(b4.z, h4.z, gb0);
          ga0 = dot2(a4.w, h4.w, ga0); gb0 = dot2(b4.w, h4.w, gb0);
        } else {
          ga1 = dot2(a4.x, h4.x, ga1); gb1 = dot2(b4.x, h4.x, gb1);
          ga1 = dot2(a4.y, h4.y, ga1); gb1 = dot2(b4.y, h4.y, gb1);
          ga1 = dot2(a4.z, h4.z, ga1); gb1 = dot2(b4.z, h4.z, gb1);
          ga1 = dot2(a4.w, h4.w, ga1); gb1 = dot2(b4.w, h4.w, gb1);
        }
      }
#pragma unroll
      for (int q = 0; q < 24; q++) {
        const uint4 h4 = *(const uint4*)&h2l[32 + 4 * q];
        if ((q & 1) == 0) {
          ga0 = dot2(wv[4 * q + 0], h4.x, ga0); gb0 = dot2(wv[96 + 4 * q + 0], h4.x, gb0);
          ga0 = dot2(wv[4 * q + 1], h4.y, ga0); gb0 = dot2(wv[96 + 4 * q + 1], h4.y, gb0);
          ga0 = dot2(wv[4 * q + 2], h4.z, ga0); gb0 = dot2(wv[96 + 4 * q + 2], h4.z, gb0);
          ga0 = dot2(wv[4 * q + 3], h4.w, ga0); gb0 = dot2(wv[96 + 4 * q + 3], h4.w, gb0);
        } else {
          ga1 = dot2(wv[4 * q + 0], h4.x, ga1); gb1 = dot2(wv[96 + 4 * q + 0], h4.x, gb1);
          ga1 = dot2(wv[4 * q + 1], h4.y, ga1); gb1 = dot2(wv[96 + 4 * q + 1], h4.y, gb1);
          ga1 = dot2(wv[4 * q + 2], h4.z, ga1); gb1 = dot2(wv[96 + 4 * q + 2], h4.z, gb1);
          ga1 = dot2(wv[4 * q + 3], h4.w, ga1); gb1 = dot2(wv[96 + 4 * q + 3], h4.w, gb1);
        }
      }
      const float ga = ga0 + ga1 + xga;  // row tid     (i- or f-gate)
      const float gb = gb0 + gb1 + xgb;  // row tid+512 (g- or o-gate)
      const float acta = sigmoid_f(ga);
      const float actb = (tid < 256) ? tanh_f(gb) : sigmoid_f(gb);
      actl[tid] = acta;
      actl[tid + 512] = actb;
      __syncthreads();  // B1: h2l reads done; acts visible
      if (tid < 256) {
        const float i_ = actl[tid];
        const float f_ = actl[256 + tid];
        const float g_ = actl[512 + tid];
        const float o_ = actl[768 + tid];
        cst = f_ * cst + i_ * g_;
        hval = o_ * tanh_f(cst);
        ((_Float16*)h2l)[tid] = (_Float16)hval;
      }
      __syncthreads();  // B2: h2l ready for next step
    }
    if (tid < 256) HH[((frame + 1) * 64 + b) * 256 + tid] = hval;
  }
}

// Hl[i][b][p] = HH[i][b]·W_lh[p] + b_lh[p]. One block per frame.
__global__ void k_hl(const float* __restrict__ HH,
                     const unsigned* __restrict__ wlh_h2,
                     const float* __restrict__ blh, float* __restrict__ Hl) {
  const int i = blockIdx.x;
  const int tid = threadIdx.x;  // 256
  __shared__ __align__(16) unsigned Ah[64 * 132];
  __shared__ __align__(16) unsigned Bh[128 * 132];
  for (int idx = tid; idx < 64 * 128; idx += 256) {
    const int r = idx >> 7, kp = idx & 127;
    const float* s = HH + ((size_t)(i * 64 + r)) * 256 + 2 * kp;
    Ah[r * 132 + kp] = pack2(s[0], s[1]);
  }
  for (int idx = tid; idx < 128 * 128; idx += 256) {
    const int o = idx >> 7, kp = idx & 127;
    Bh[o * 132 + kp] = wlh_h2[o * 128 + kp];
  }
  __syncthreads();
  const int ry = tid >> 4, px = tid & 15;
  float acc[4][8];
#pragma unroll
  for (int k = 0; k < 4; k++)
#pragma unroll
    for (int j = 0; j < 8; j++) acc[k][j] = 0.f;
  for (int kb = 0; kb < 32; kb++) {
    uint4 a4[4], b4[8];
#pragma unroll
    for (int k = 0; k < 4; k++) a4[k] = *(const uint4*)&Ah[(16 * k + ry) * 132 + 4 * kb];
#pragma unroll
    for (int j = 0; j < 8; j++) b4[j] = *(const uint4*)&Bh[(16 * j + px) * 132 + 4 * kb];
#pragma unroll
    for (int k = 0; k < 4; k++)
#pragma unroll
      for (int j = 0; j < 8; j++) {
        acc[k][j] = dot2(a4[k].x, b4[j].x, acc[k][j]);
        acc[k][j] = dot2(a4[k].y, b4[j].y, acc[k][j]);
        acc[k][j] = dot2(a4[k].z, b4[j].z, acc[k][j]);
        acc[k][j] = dot2(a4[k].w, b4[j].w, acc[k][j]);
      }
  }
#pragma unroll
  for (int k = 0; k < 4; k++)
#pragma unroll
    for (int j = 0; j < 8; j++)
      Hl[(i * 64 + 16 * k + ry) * 128 + 16 * j + px] = acc[k][j] + blh[16 * j + px];
}

// Fused Vp GEMM + z. Rows = flattened (b,g) within frame i (2304 rows, tiles
// of 128). z[b,g] = sum_p w[p]*tanh(Hl[b,p] + Vp[b,g,p]).
__global__ void k_att_z(const float* __restrict__ cnn,
                        const unsigned* __restrict__ wcn_h2,
                        const float* __restrict__ bcn,
                        const float* __restrict__ Hl,
                        const float* __restrict__ wwt,
                        float* __restrict__ zbuf) {
  const int bid = blockIdx.x;  // 576 = 32 frames * 18 row tiles
  const int i = bid / 18, rt = bid - 18 * i;
  const int tid = threadIdx.x;  // 256
  const int r0 = rt * 128;
  __shared__ __align__(16) unsigned As[128 * 132];
  __shared__ __align__(16) unsigned Bs[128 * 132];
  __shared__ float zpart[128 * 16];
  __shared__ float Hls[5 * 128];
  __shared__ float wws[128];
  __shared__ float bcs[128];

  for (int idx = tid; idx < 128 * 128; idx += 256) {
    const int r = idx >> 7, kp = idx & 127;
    const int R = r0 + r;
    const int b = R / 36, g = R - b * 36;
    const float* src = cnn + (((size_t)b * 32 + i) * 36 + g) * 256 + 2 * kp;
    As[r * 132 + kp] = pack2(src[0], src[1]);
  }
  for (int idx = tid; idx < 128 * 128; idx += 256) {
    const int o = idx >> 7, kp = idx & 127;
    Bs[o * 132 + kp] = wcn_h2[o * 128 + kp];
  }
  const int bmin = r0 / 36;
  for (int idx = tid; idx < 5 * 128; idx += 256) {
    const int bb = bmin + (idx >> 7);
    if (bb < 64) Hls[idx] = Hl[(i * 64 + bb) * 128 + (idx & 127)];
  }
  if (tid < 128) {
    wws[tid] = wwt[tid];
    bcs[tid] = bcn[tid];
  }
  __syncthreads();

  const int ry = tid >> 4, px = tid & 15;
  float acc[8][8];
#pragma unroll
  for (int k = 0; k < 8; k++)
#pragma unroll
    for (int j = 0; j < 8; j++) acc[k][j] = bcs[16 * j + px];
  for (int kb = 0; kb < 32; kb++) {
    uint4 a4[8], b4[8];
#pragma unroll
    for (int k = 0; k < 8; k++) a4[k] = *(const uint4*)&As[(16 * k + ry) * 132 + 4 * kb];
#pragma unroll
    for (int j = 0; j < 8; j++) b4[j] = *(const uint4*)&Bs[(16 * j + px) * 132 + 4 * kb];
#pragma unroll
    for (int k = 0; k < 8; k++)
#pragma unroll
      for (int j = 0; j < 8; j++) {
        acc[k][j] = dot2(a4[k].x, b4[j].x, acc[k][j]);
        acc[k][j] = dot2(a4[k].y, b4[j].y, acc[k][j]);
        acc[k][j] = dot2(a4[k].z, b4[j].z, acc[k][j]);
        acc[k][j] = dot2(a4[k].w, b4[j].w, acc[k][j]);
      }
  }
#pragma unroll
  for (int k = 0; k < 8; k++) {
    const int r = 16 * k + ry;
    const int R = r0 + r;
    const int b = R / 36;
    const float* HlRow = &Hls[(b - bmin) * 128];
    float zp = 0.f;
#pragma unroll
    for (int j = 0; j < 8; j++) {
      const int po = 16 * j + px;
      zp += wws[po] * tanh_f(HlRow[po] + acc[k][j]);
    }
    zpart[r * 16 + px] = zp;
  }
  __syncthreads();
  if (tid < 128) {
    float z = 0.f;
#pragma unroll
    for (int x = 0; x < 16; x++) z += zpart[tid * 16 + x];
    const int R = r0 + tid;
    const int b = R / 36, g = R - b * 36;
    zbuf[(i * 64 + b) * 36 + g] = z;
  }
}

// Scrambled softmax + weighted V sum; builds fc = [spatial_feat | h_next].
__global__ void k_att_sf(const float* __restrict__ cnn,
                         const float* __restrict__ zbuf,
                         const float* __restrict__ HH,
                         float* __restrict__ fc) {
  const int bid = blockIdx.x;  // 2048 = i*64 + b
  const int i = bid >> 6, b = bid & 63;
  const int tid = threadIdx.x;  // 256
  __shared__ float zl[36];
  __shared__ float el[40];
  __shared__ float red[1];
  if (tid < 36) {
    const int idx = b * 36 + tid;  // scramble: z.T.reshape(64,36)
    zl[tid] = zbuf[(i * 64 + (idx & 63)) * 36 + (idx >> 6)];
  }
  __syncthreads();
  if (tid == 0) {
    float m = zl[0];
    for (int g = 1; g < 36; g++) m = fmaxf(m, zl[g]);
    float s = 0.f;
    for (int g = 0; g < 36; g++) {
      const float e = __expf(zl[g] - m);
      el[g] = e;
      s += e;
    }
    red[0] = 1.f / s;
  }
  __syncthreads();
  const float inv = red[0];
  float accv = 0.f;
  const float* Vb = cnn + (((size_t)b * 32 + i) * 36) * 256 + tid;
#pragma unroll 4
  for (int g = 0; g < 36; g++) accv += el[g] * Vb[g * 256];
  fc[(size_t)bid * 512 + tid] = accv * inv;
  fc[(size_t)bid * 512 + 256 + tid] = HH[((i + 1) * 64 + b) * 256 + tid];
}

// MLP layers 1/2: (2048,512)@(512,512)+b, output packed f16 pairs.
template <int SRCMODE>  // 0: f32 src (fc), 1: packed-h2 src
__global__ void k_mlp(const void* __restrict__ src,
                      const unsigned* __restrict__ wh2,
                      const float* __restrict__ bias,
                      unsigned* __restrict__ dst) {
  const int bid = blockIdx.x;  // 128 = 32 n-tiles * 4 o-tiles
  const int nb = bid >> 2, ob = bid & 3;
  const int n0 = nb * 64, o0 = ob * 128;
  const int tid = threadIdx.x;
  __shared__ __align__(16) unsigned As[64 * 132];
  __shared__ __align__(16) unsigned Bs[128 * 132];
  const int ry = tid >> 4, px = tid & 15;
  float acc[4][8];
#pragma unroll
  for (int k = 0; k < 4; k++)
#pragma unroll
    for (int m = 0; m < 8; m++)
      acc[k][m] = bias[o0 + 32 * (m >> 1) + 2 * px + (m & 1)];
  for (int kc = 0; kc < 2; kc++) {
    __syncthreads();
    for (int idx = tid; idx < 64 * 128; idx += 256) {
      const int r = idx >> 7, kp = idx & 127;
      if (SRCMODE == 0) {
        const float* s = (const float*)src + ((size_t)(n0 + r)) * 512 + kc * 256 + 2 * kp;
        As[r * 132 + kp] = pack2(s[0], s[1]);
      } else {
        As[r * 132 + kp] = ((const unsigned*)src)[((size_t)(n0 + r)) * 256 + kc * 128 + kp];
      }
    }
    for (int idx = tid; idx < 128 * 128; idx += 256) {
      const int o = idx >> 7, kp = idx & 127;
      Bs[o * 132 + kp] = wh2[((size_t)(o0 + o)) * 256 + kc * 128 + kp];
    }
    __syncthreads();
    for (int kb = 0; kb < 32; kb++) {
      uint4 a4[4], b4[8];
#pragma unroll
      for (int k = 0; k < 4; k++)
        a4[k] = *(const uint4*)&As[(16 * k + ry) * 132 + 4 * kb];
#pragma unroll
      for (int m = 0; m < 8; m++)
        b4[m] = *(const uint4*)&Bs[(32 * (m >> 1) + 2 * px + (m & 1)) * 132 + 4 * kb];
#pragma unroll
      for (int k = 0; k < 4; k++)
#pragma unroll
        for (int m = 0; m < 8; m++) {
          acc[k][m] = dot2(a4[k].x, b4[m].x, acc[k][m]);
          acc[k][m] = dot2(a4[k].y, b4[m].y, acc[k][m]);
          acc[k][m] = dot2(a4[k].z, b4[m].z, acc[k][m]);
          acc[k][m] = dot2(a4[k].w, b4[m].w, acc[k][m]);
        }
    }
  }
#pragma unroll
  for (int k = 0; k < 4; k++) {
    const int n = n0 + 16 * k + ry;
#pragma unroll
    for (int j = 0; j < 4; j++)
      dst[(size_t)n * 256 + (o0 >> 1) + 16 * j + px] =
          pack2(acc[k][2 * j], acc[k][2 * j + 1]);
  }
}

// Final layer: (2048,512) -> 6 classes.
__global__ void k_mlp3(const unsigned* __restrict__ y2h2,
                       const unsigned* __restrict__ wm3h2,
                       const float* __restrict__ bm3,
                       float* __restrict__ out) {
  const int nb = blockIdx.x;  // 32
  const int tid = threadIdx.x;
  __shared__ __align__(16) unsigned Ys[64 * 256];
  __shared__ __align__(16) unsigned Ws[6 * 256];
  for (int idx = tid; idx < 64 * 256; idx += 256)
    Ys[idx] = y2h2[(size_t)nb * 64 * 256 + idx];
  for (int idx = tid; idx < 6 * 256; idx += 256) Ws[idx] = wm3h2[idx];
  __syncthreads();
  for (int u = 0; u < 2; u++) {
    const int idx = tid + u * 256;
    if (idx < 384) {
      const int nl = idx / 6, c = idx - 6 * nl;
      float a0 = 0.f, a1 = 0.f;
#pragma unroll
      for (int kq = 0; kq < 64; kq++) {
        const uint4 y4 = *(const uint4*)&Ys[nl * 256 + 4 * kq];
        const uint4 w4 = *(const uint4*)&Ws[c * 256 + 4 * kq];
        a0 = dot2(y4.x, w4.x, a0);
        a1 = dot2(y4.y, w4.y, a1);
        a0 = dot2(y4.z, w4.z, a0);
        a1 = dot2(y4.w, w4.w, a1);
      }
      out[(size_t)(nb * 64 + nl) * 6 + c] = a0 + a1 + bm3[c];
    }
  }
}

// ---------------------------------------------------------------------------
extern "C" void kernel_launch(void* const* d_in, const int* in_sizes, int n_in,
                              void* d_out, int out_size, void* d_ws,
                              size_t ws_size, hipStream_t stream) {
  (void)in_sizes; (void)n_in; (void)out_size; (void)ws_size;
  const float* cnn  = (const float*)d_in[0];
  const float* gaze = (const float*)d_in[1];
  const float* W_lh = (const float*)d_in[2];
  const float* b_lh = (const float*)d_in[3];
  const float* W_cn = (const float*)d_in[4];
  const float* b_cn = (const float*)d_in[5];
  const float* w_wt = (const float*)d_in[6];
  const float* Wih  = (const float*)d_in[7];
  const float* Whh  = (const float*)d_in[8];
  const float* bih  = (const float*)d_in[9];
  const float* bhh  = (const float*)d_in[10];
  const float* Wh1  = (const float*)d_in[11];
  const float* bh1  = (const float*)d_in[12];
  const float* Wh2  = (const float*)d_in[13];
  const float* bh2  = (const float*)d_in[14];
  const float* Wc1  = (const float*)d_in[15];
  const float* bc1  = (const float*)d_in[16];
  const float* Wc2  = (const float*)d_in[17];
  const float* bc2  = (const float*)d_in[18];
  const float* Wm1  = (const float*)d_in[19];
  const float* bm1  = (const float*)d_in[20];
  const float* Wm2  = (const float*)d_in[21];
  const float* bm2  = (const float*)d_in[22];
  const float* Wm3  = (const float*)d_in[23];
  const float* bm3  = (const float*)d_in[24];
  float* out = (float*)d_out;

  unsigned* W = (unsigned*)d_ws;
  float* Wf = (float*)d_ws;
  // workspace offsets in dwords
  const size_t O_xg  = 0;                    // [31][64][1024] f32
  const size_t O_wv  = 2031616;              // [192][512]     u32
  const size_t O_wl  = O_wv + 98304;         // [1024][32]     u32
  const size_t O_HH  = O_wl + 32768;         // [33][64][256]  f32
  const size_t O_c0  = O_HH + 540672;        // [64][256]      f32
  const size_t O_Hl  = O_c0 + 16384;         // [32][64][128]  f32
  const size_t O_z   = O_Hl + 262144;        // [32][64][36]   f32
  const size_t O_fc  = O_z + 73728;          // [2048][512]    f32
  const size_t O_y1  = O_fc + 1048576;       // [2048][256]    u32 (h2)
  const size_t O_y2  = O_y1 + 524288;        // [2048][256]    u32 (h2)
  const size_t O_wcn = O_y2 + 524288;        // [128][128]     u32
  const size_t O_wlh = O_wcn + 16384;
  const size_t O_wm1 = O_wlh + 16384;        // [512][256]
  const size_t O_wm2 = O_wm1 + 131072;
  const size_t O_wm3 = O_wm2 + 131072;       // [6][256]

  float* xg  = Wf + O_xg;
  float* HH  = Wf + O_HH;
  float* c0f = Wf + O_c0;
  float* Hlf = Wf + O_Hl;
  float* zf  = Wf + O_z;
  float* fcf = Wf + O_fc;

  // --- prepacking (independent) ---
  k_pack_wv<<<512, 256, 0, stream>>>(Whh, W + O_wv, W + O_wl);
  k_packh2<<<64, 256, 0, stream>>>(W_cn, W + O_wcn, 16384);
  k_packh2<<<64, 256, 0, stream>>>(W_lh, W + O_wlh, 16384);
  k_packh2<<<512, 256, 0, stream>>>(Wm1, W + O_wm1, 131072);
  k_packh2<<<512, 256, 0, stream>>>(Wm2, W + O_wm2, 131072);
  k_packh2<<<6, 256, 0, stream>>>(Wm3, W + O_wm3, 1536);
  k_xg<<<7936, 256, 0, stream>>>(gaze, Wih, bih, bhh, xg);
  k_init<<<64, 256, 0, stream>>>(gaze, Wh1, bh1, Wh2, bh2, Wc1, bc1, Wc2, bc2,
                                 HH, c0f);
  // --- the sequential chain ---
  k_lstm<<<64, 512, 0, stream>>>(xg, W + O_wv, W + O_wl, c0f, HH);
  // --- batched attention ---
  k_hl<<<32, 256, 0, stream>>>(HH, W + O_wlh, b_lh, Hlf);
  k_att_z<<<576, 256, 0, stream>>>(cnn, W + O_wcn, b_cn, Hlf, w_wt, zf);
  k_att_sf<<<2048, 256, 0, stream>>>(cnn, zf, HH, fcf);
  // --- batched MLP ---
  k_mlp<0><<<128, 256, 0, stream>>>((const void*)fcf, W + O_wm1, bm1, W + O_y1);
  k_mlp<1><<<128, 256, 0, stream>>>((const void*)(W + O_y1), W + O_wm2, bm2, W + O_y2);
  k_mlp3<<<32, 256, 0, stream>>>(W + O_y2, W + O_wm3, bm3, out);
}

// Round 3
// 5233.345 us; speedup vs baseline: 1.0819x; 1.0006x over previous
//
#include <hip/hip_runtime.h>
#include <math.h>

// ---------------------------------------------------------------------------
// SpatialAttentionModel on MI355X.
// (1) init h0/c0, (2) precompute LSTM input projections, (3) ONE sequential
// LSTM chain (497 steps) recording h at frame boundaries, (4) batched
// attention, (5) batched 3-layer MLP.
// BS=64, T=32, GRID=36, FEAT=256, HID=256, PROJ=128, NCLS=6, MLP_IN=512.
// R3: pin k_lstm to 2 waves/EU via amdgpu_waves_per_eu(2,2) -> 256-VGPR cap.
// (R1 launch_bounds(512,2) and R2 launch_bounds(512) both produced a 128-reg
// cap = 4-waves/EU backend target, spilling the 192-dword weight array.)
// ---------------------------------------------------------------------------

typedef _Float16 h2_t __attribute__((ext_vector_type(2)));

#if __has_builtin(__builtin_amdgcn_fdot2)
#define HAVE_FDOT2 1
#else
#define HAVE_FDOT2 0
#endif

__device__ __forceinline__ float dot2(unsigned w, unsigned h, float acc) {
#if HAVE_FDOT2
  return __builtin_amdgcn_fdot2(__builtin_bit_cast(h2_t, w),
                                __builtin_bit_cast(h2_t, h), acc, false);
#else
  h2_t a = __builtin_bit_cast(h2_t, w);
  h2_t b = __builtin_bit_cast(h2_t, h);
  return acc + (float)a[0] * (float)b[0] + (float)a[1] * (float)b[1];
#endif
}

__device__ __forceinline__ unsigned pack2(float a, float b) {
  h2_t p;
  p[0] = (_Float16)a;
  p[1] = (_Float16)b;
  return __builtin_bit_cast(unsigned, p);
}

__device__ __forceinline__ float sigmoid_f(float x) {
  return __builtin_amdgcn_rcpf(1.f + __expf(-x));
}
__device__ __forceinline__ float tanh_f(float x) {
  return 1.f - 2.f * __builtin_amdgcn_rcpf(1.f + __expf(2.f * x));
}

// ---------------------------------------------------------------------------
// Pack Whh into the LSTM kernel's two layouts:
//  wv_pack[m][tau] (m<192, tau<512): VGPR-resident pairs 32..127 of rows tau
//  (m<96) and tau+512 (m>=96).
//  wlds_pack[row][p] (p<32): pairs 0..31 of every row (read from LDS).
__global__ void k_pack_wv(const float* __restrict__ Whh,
                          unsigned* __restrict__ wv_pack,
                          unsigned* __restrict__ wlds_pack) {
  const int idx = blockIdx.x * 256 + threadIdx.x;  // < 131072
  if (idx < 98304) {
    const int m = idx >> 9, tau = idx & 511;
    const int row = (m < 96) ? tau : tau + 512;
    const int pair = 32 + ((m < 96) ? m : m - 96);
    wv_pack[idx] = pack2(Whh[row * 256 + 2 * pair], Whh[row * 256 + 2 * pair + 1]);
  } else {
    const int j = idx - 98304;  // < 32768
    const int row = j >> 5, pair = j & 31;
    wlds_pack[j] = pack2(Whh[row * 256 + 2 * pair], Whh[row * 256 + 2 * pair + 1]);
  }
}

// Generic f32 -> packed-f16-pair converter (contiguous rows, even cols).
__global__ void k_packh2(const float* __restrict__ src,
                         unsigned* __restrict__ dst, int n) {
  const int i = blockIdx.x * 256 + threadIdx.x;
  if (i < n) dst[i] = pack2(src[2 * i], src[2 * i + 1]);
}

// xg[t][b][j] = gaze[b,t,:]·Wih[j,:] + bih[j] + bhh[j],  t in [0,31)
__global__ void k_xg(const float* __restrict__ gaze,
                     const float* __restrict__ Wih,
                     const float* __restrict__ bih,
                     const float* __restrict__ bhh,
                     float* __restrict__ xg) {
  const int idx = blockIdx.x * 256 + threadIdx.x;
  if (idx >= 31 * 64 * 1024) return;
  const int j = idx & 1023;
  const int b = (idx >> 10) & 63;
  const int t = idx >> 16;
  const float* gz = gaze + (b * 32 + t) * 3;
  xg[idx] = gz[0] * Wih[j * 3 + 0] + gz[1] * Wih[j * 3 + 1] +
            gz[2] * Wih[j * 3 + 2] + bih[j] + bhh[j];
}

// h0/c0: h = tanh(tanh( tanh(mg@Wh1.T+bh1) @ Wh2.T + bh2 )), same for c.
__global__ void k_init(const float* __restrict__ gaze,
                       const float* __restrict__ Wh1, const float* __restrict__ bh1,
                       const float* __restrict__ Wh2, const float* __restrict__ bh2,
                       const float* __restrict__ Wc1, const float* __restrict__ bc1,
                       const float* __restrict__ Wc2, const float* __restrict__ bc2,
                       float* __restrict__ HH, float* __restrict__ c0) {
  const int b = blockIdx.x;
  const int tid = threadIdx.x;  // 256
  __shared__ float mg[3];
  __shared__ float t1h[256], t1c[256];
  if (tid < 3) {
    float s = 0.f;
    for (int t = 0; t < 32; t++) s += gaze[(b * 32 + t) * 3 + tid];
    mg[tid] = s * (1.f / 32.f);
  }
  __syncthreads();
  {
    float a = mg[0] * Wh1[tid * 3 + 0] + mg[1] * Wh1[tid * 3 + 1] +
              mg[2] * Wh1[tid * 3 + 2] + bh1[tid];
    t1h[tid] = tanhf(a);
    float c = mg[0] * Wc1[tid * 3 + 0] + mg[1] * Wc1[tid * 3 + 1] +
              mg[2] * Wc1[tid * 3 + 2] + bc1[tid];
    t1c[tid] = tanhf(c);
  }
  __syncthreads();
  float s1 = bh2[tid], s2 = bc2[tid];
  for (int k = 0; k < 256; k++) {
    s1 += t1h[k] * Wh2[tid * 256 + k];
    s2 += t1c[k] * Wc2[tid * 256 + k];
  }
  HH[b * 256 + tid] = tanhf(tanhf(s1));  // HH[0][b][k]
  c0[b * 256 + tid] = tanhf(tanhf(s2));
}

// ---------------------------------------------------------------------------
// The sequential LSTM chain. One block per batch element. 512 threads;
// thread tau owns gate rows tau and tau+512. f16 weights: pairs 32..127 in
// VGPRs (192 dwords), pairs 0..31 in LDS (stride-36 rows). h broadcast from
// LDS as packed-f16 uint4; h written back as ds_write_b16.
// LDS 152 KB limits to 1 block/CU = 2 waves/EU, so pin the register budget
// there: amdgpu_waves_per_eu(2,2) -> 256-VGPR cap, no spill.
__global__ __launch_bounds__(512)
__attribute__((amdgpu_waves_per_eu(2, 2))) void k_lstm(
    const float* __restrict__ xg, const unsigned* __restrict__ wv_pack,
    const unsigned* __restrict__ wlds_pack, const float* __restrict__ c0,
    float* __restrict__ HH) {
  const int b = blockIdx.x;
  const int tid = threadIdx.x;
  __shared__ __align__(16) unsigned wlds[1024 * 36];  // 147456 B
  __shared__ float actl[1024];
  __shared__ __align__(16) unsigned h2l[128];

  for (int i = tid; i < 1024 * 32; i += 512) {
    const int row = i >> 5, p = i & 31;
    wlds[row * 36 + p] = wlds_pack[i];
  }
  unsigned wv[192];
#pragma unroll
  for (int m = 0; m < 192; m++) wv[m] = wv_pack[m * 512 + tid];

  float cst = (tid < 256) ? c0[b * 256 + tid] : 0.f;
  if (tid < 256) ((_Float16*)h2l)[tid] = (_Float16)HH[b * 256 + tid];
  __syncthreads();

  const unsigned* wA = &wlds[tid * 36];
  const unsigned* wB = &wlds[(tid + 512) * 36];
  float hval = 0.f;

  for (int frame = 0; frame < 32; frame++) {
    const int L = frame ? frame : 1;
    for (int t = 0; t < L; t++) {
      const float* xgt = xg + (t * 64 + b) * 1024;
      const float xga = xgt[tid];
      const float xgb = xgt[tid + 512];
      float ga0 = 0.f, ga1 = 0.f, gb0 = 0.f, gb1 = 0.f;
#pragma unroll
      for (int q = 0; q < 8; q++) {
        const uint4 h4 = *(const uint4*)&h2l[4 * q];
        const uint4 a4 = *(const uint4*)&wA[4 * q];
        const uint4 b4 = *(const uint4*)&wB[4 * q];
        if ((q & 1) == 0) {
          ga0 = dot2(a4.x, h4.x, ga0); gb0 = dot2(b4.x, h4.x, gb0);
          ga0 = dot2(a4.y, h4.y, ga0); gb0 = dot2(b4.y, h4.y, gb0);
          ga0 = dot2(a4.z, h4.z, ga0); gb0 = dot2(b4.z, h4.z, gb0);
          ga0 = dot2(a4.w, h4.w, ga0); gb0 = dot2(b4.w, h4.w, gb0);
        } else {
          ga1 = dot2(a4.x, h4.x, ga1); gb1 = dot2(b4.x, h4.x, gb1);
          ga1 = dot2(a4.y, h4.y, ga1); gb1 = dot2(b4.y, h4.y, gb1);
          ga1 = dot2(a4.z, h4.z, ga1); gb1 = dot2(b4.z, h4.z, gb1);
          ga1 = dot2(a4.w, h4.w, ga1); gb1 = dot2(b4.w, h4.w, gb1);
        }
      }
#pragma unroll
      for (int q = 0; q < 24; q++) {
        const uint4 h4 = *(const uint4*)&h2l[32 + 4 * q];
        if ((q & 1) == 0) {
          ga0 = dot2(wv[4 * q + 0], h4.x, ga0); gb0 = dot2(wv[96 + 4 * q + 0], h4.x, gb0);
          ga0 = dot2(wv[4 * q + 1], h4.y, ga0); gb0 = dot2(wv[96 + 4 * q + 1], h4.y, gb0);
          ga0 = dot2(wv[4 * q + 2], h4.z, ga0); gb0 = dot2(wv[96 + 4 * q + 2], h4.z, gb0);
          ga0 = dot2(wv[4 * q + 3], h4.w, ga0); gb0 = dot2(wv[96 + 4 * q + 3], h4.w, gb0);
        } else {
          ga1 = dot2(wv[4 * q + 0], h4.x, ga1); gb1 = dot2(wv[96 + 4 * q + 0], h4.x, gb1);
          ga1 = dot2(wv[4 * q + 1], h4.y, ga1); gb1 = dot2(wv[96 + 4 * q + 1], h4.y, gb1);
          ga1 = dot2(wv[4 * q + 2], h4.z, ga1); gb1 = dot2(wv[96 + 4 * q + 2], h4.z, gb1);
          ga1 = dot2(wv[4 * q + 3], h4.w, ga1); gb1 = dot2(wv[96 + 4 * q + 3], h4.w, gb1);
        }
      }
      const float ga = ga0 + ga1 + xga;  // row tid     (i- or f-gate)
      const float gb = gb0 + gb1 + xgb;  // row tid+512 (g- or o-gate)
      const float acta = sigmoid_f(ga);
      const float actb = (tid < 256) ? tanh_f(gb) : sigmoid_f(gb);
      actl[tid] = acta;
      actl[tid + 512] = actb;
      __syncthreads();  // B1: h2l reads done; acts visible
      if (tid < 256) {
        const float i_ = actl[tid];
        const float f_ = actl[256 + tid];
        const float g_ = actl[512 + tid];
        const float o_ = actl[768 + tid];
        cst = f_ * cst + i_ * g_;
        hval = o_ * tanh_f(cst);
        ((_Float16*)h2l)[tid] = (_Float16)hval;
      }
      __syncthreads();  // B2: h2l ready for next step
    }
    if (tid < 256) HH[((frame + 1) * 64 + b) * 256 + tid] = hval;
  }
}

// Hl[i][b][p] = HH[i][b]·W_lh[p] + b_lh[p]. One block per frame.
__global__ void k_hl(const float* __restrict__ HH,
                     const unsigned* __restrict__ wlh_h2,
                     const float* __restrict__ blh, float* __restrict__ Hl) {
  const int i = blockIdx.x;
  const int tid = threadIdx.x;  // 256
  __shared__ __align__(16) unsigned Ah[64 * 132];
  __shared__ __align__(16) unsigned Bh[128 * 132];
  for (int idx = tid; idx < 64 * 128; idx += 256) {
    const int r = idx >> 7, kp = idx & 127;
    const float* s = HH + ((size_t)(i * 64 + r)) * 256 + 2 * kp;
    Ah[r * 132 + kp] = pack2(s[0], s[1]);
  }
  for (int idx = tid; idx < 128 * 128; idx += 256) {
    const int o = idx >> 7, kp = idx & 127;
    Bh[o * 132 + kp] = wlh_h2[o * 128 + kp];
  }
  __syncthreads();
  const int ry = tid >> 4, px = tid & 15;
  float acc[4][8];
#pragma unroll
  for (int k = 0; k < 4; k++)
#pragma unroll
    for (int j = 0; j < 8; j++) acc[k][j] = 0.f;
  for (int kb = 0; kb < 32; kb++) {
    uint4 a4[4], b4[8];
#pragma unroll
    for (int k = 0; k < 4; k++) a4[k] = *(const uint4*)&Ah[(16 * k + ry) * 132 + 4 * kb];
#pragma unroll
    for (int j = 0; j < 8; j++) b4[j] = *(const uint4*)&Bh[(16 * j + px) * 132 + 4 * kb];
#pragma unroll
    for (int k = 0; k < 4; k++)
#pragma unroll
      for (int j = 0; j < 8; j++) {
        acc[k][j] = dot2(a4[k].x, b4[j].x, acc[k][j]);
        acc[k][j] = dot2(a4[k].y, b4[j].y, acc[k][j]);
        acc[k][j] = dot2(a4[k].z, b4[j].z, acc[k][j]);
        acc[k][j] = dot2(a4[k].w, b4[j].w, acc[k][j]);
      }
  }
#pragma unroll
  for (int k = 0; k < 4; k++)
#pragma unroll
    for (int j = 0; j < 8; j++)
      Hl[(i * 64 + 16 * k + ry) * 128 + 16 * j + px] = acc[k][j] + blh[16 * j + px];
}

// Fused Vp GEMM + z. Rows = flattened (b,g) within frame i (2304 rows, tiles
// of 128). z[b,g] = sum_p w[p]*tanh(Hl[b,p] + Vp[b,g,p]).
__global__ void k_att_z(const float* __restrict__ cnn,
                        const unsigned* __restrict__ wcn_h2,
                        const float* __restrict__ bcn,
                        const float* __restrict__ Hl,
                        const float* __restrict__ wwt,
                        float* __restrict__ zbuf) {
  const int bid = blockIdx.x;  // 576 = 32 frames * 18 row tiles
  const int i = bid / 18, rt = bid - 18 * i;
  const int tid = threadIdx.x;  // 256
  const int r0 = rt * 128;
  __shared__ __align__(16) unsigned As[128 * 132];
  __shared__ __align__(16) unsigned Bs[128 * 132];
  __shared__ float zpart[128 * 16];
  __shared__ float Hls[5 * 128];
  __shared__ float wws[128];
  __shared__ float bcs[128];

  for (int idx = tid; idx < 128 * 128; idx += 256) {
    const int r = idx >> 7, kp = idx & 127;
    const int R = r0 + r;
    const int b = R / 36, g = R - b * 36;
    const float* src = cnn + (((size_t)b * 32 + i) * 36 + g) * 256 + 2 * kp;
    As[r * 132 + kp] = pack2(src[0], src[1]);
  }
  for (int idx = tid; idx < 128 * 128; idx += 256) {
    const int o = idx >> 7, kp = idx & 127;
    Bs[o * 132 + kp] = wcn_h2[o * 128 + kp];
  }
  const int bmin = r0 / 36;
  for (int idx = tid; idx < 5 * 128; idx += 256) {
    const int bb = bmin + (idx >> 7);
    if (bb < 64) Hls[idx] = Hl[(i * 64 + bb) * 128 + (idx & 127)];
  }
  if (tid < 128) {
    wws[tid] = wwt[tid];
    bcs[tid] = bcn[tid];
  }
  __syncthreads();

  const int ry = tid >> 4, px = tid & 15;
  float acc[8][8];
#pragma unroll
  for (int k = 0; k < 8; k++)
#pragma unroll
    for (int j = 0; j < 8; j++) acc[k][j] = bcs[16 * j + px];
  for (int kb = 0; kb < 32; kb++) {
    uint4 a4[8], b4[8];
#pragma unroll
    for (int k = 0; k < 8; k++) a4[k] = *(const uint4*)&As[(16 * k + ry) * 132 + 4 * kb];
#pragma unroll
    for (int j = 0; j < 8; j++) b4[j] = *(const uint4*)&Bs[(16 * j + px) * 132 + 4 * kb];
#pragma unroll
    for (int k = 0; k < 8; k++)
#pragma unroll
      for (int j = 0; j < 8; j++) {
        acc[k][j] = dot2(a4[k].x, b4[j].x, acc[k][j]);
        acc[k][j] = dot2(a4[k].y, b4[j].y, acc[k][j]);
        acc[k][j] = dot2(a4[k].z, b4[j].z, acc[k][j]);
        acc[k][j] = dot2(a4[k].w, b4[j].w, acc[k][j]);
      }
  }
#pragma unroll
  for (int k = 0; k < 8; k++) {
    const int r = 16 * k + ry;
    const int R = r0 + r;
    const int b = R / 36;
    const float* HlRow = &Hls[(b - bmin) * 128];
    float zp = 0.f;
#pragma unroll
    for (int j = 0; j < 8; j++) {
      const int po = 16 * j + px;
      zp += wws[po] * tanh_f(HlRow[po] + acc[k][j]);
    }
    zpart[r * 16 + px] = zp;
  }
  __syncthreads();
  if (tid < 128) {
    float z = 0.f;
#pragma unroll
    for (int x = 0; x < 16; x++) z += zpart[tid * 16 + x];
    const int R = r0 + tid;
    const int b = R / 36, g = R - b * 36;
    zbuf[(i * 64 + b) * 36 + g] = z;
  }
}

// Scrambled softmax + weighted V sum; builds fc = [spatial_feat | h_next].
__global__ void k_att_sf(const float* __restrict__ cnn,
                         const float* __restrict__ zbuf,
                         const float* __restrict__ HH,
                         float* __restrict__ fc) {
  const int bid = blockIdx.x;  // 2048 = i*64 + b
  const int i = bid >> 6, b = bid & 63;
  const int tid = threadIdx.x;  // 256
  __shared__ float zl[36];
  __shared__ float el[40];
  __shared__ float red[1];
  if (tid < 36) {
    const int idx = b * 36 + tid;  // scramble: z.T.reshape(64,36)
    zl[tid] = zbuf[(i * 64 + (idx & 63)) * 36 + (idx >> 6)];
  }
  __syncthreads();
  if (tid == 0) {
    float m = zl[0];
    for (int g = 1; g < 36; g++) m = fmaxf(m, zl[g]);
    float s = 0.f;
    for (int g = 0; g < 36; g++) {
      const float e = __expf(zl[g] - m);
      el[g] = e;
      s += e;
    }
    red[0] = 1.f / s;
  }
  __syncthreads();
  const float inv = red[0];
  float accv = 0.f;
  const float* Vb = cnn + (((size_t)b * 32 + i) * 36) * 256 + tid;
#pragma unroll 4
  for (int g = 0; g < 36; g++) accv += el[g] * Vb[g * 256];
  fc[(size_t)bid * 512 + tid] = accv * inv;
  fc[(size_t)bid * 512 + 256 + tid] = HH[((i + 1) * 64 + b) * 256 + tid];
}

// MLP layers 1/2: (2048,512)@(512,512)+b, output packed f16 pairs.
template <int SRCMODE>  // 0: f32 src (fc), 1: packed-h2 src
__global__ void k_mlp(const void* __restrict__ src,
                      const unsigned* __restrict__ wh2,
                      const float* __restrict__ bias,
                      unsigned* __restrict__ dst) {
  const int bid = blockIdx.x;  // 128 = 32 n-tiles * 4 o-tiles
  const int nb = bid >> 2, ob = bid & 3;
  const int n0 = nb * 64, o0 = ob * 128;
  const int tid = threadIdx.x;
  __shared__ __align__(16) unsigned As[64 * 132];
  __shared__ __align__(16) unsigned Bs[128 * 132];
  const int ry = tid >> 4, px = tid & 15;
  float acc[4][8];
#pragma unroll
  for (int k = 0; k < 4; k++)
#pragma unroll
    for (int m = 0; m < 8; m++)
      acc[k][m] = bias[o0 + 32 * (m >> 1) + 2 * px + (m & 1)];
  for (int kc = 0; kc < 2; kc++) {
    __syncthreads();
    for (int idx = tid; idx < 64 * 128; idx += 256) {
      const int r = idx >> 7, kp = idx & 127;
      if (SRCMODE == 0) {
        const float* s = (const float*)src + ((size_t)(n0 + r)) * 512 + kc * 256 + 2 * kp;
        As[r * 132 + kp] = pack2(s[0], s[1]);
      } else {
        As[r * 132 + kp] = ((const unsigned*)src)[((size_t)(n0 + r)) * 256 + kc * 128 + kp];
      }
    }
    for (int idx = tid; idx < 128 * 128; idx += 256) {
      const int o = idx >> 7, kp = idx & 127;
      Bs[o * 132 + kp] = wh2[((size_t)(o0 + o)) * 256 + kc * 128 + kp];
    }
    __syncthreads();
    for (int kb = 0; kb < 32; kb++) {
      uint4 a4[4], b4[8];
#pragma unroll
      for (int k = 0; k < 4; k++)
        a4[k] = *(const uint4*)&As[(16 * k + ry) * 132 + 4 * kb];
#pragma unroll
      for (int m = 0; m < 8; m++)
        b4[m] = *(const uint4*)&Bs[(32 * (m >> 1) + 2 * px + (m & 1)) * 132 + 4 * kb];
#pragma unroll
      for (int k = 0; k < 4; k++)
#pragma unroll
        for (int m = 0; m < 8; m++) {
          acc[k][m] = dot2(a4[k].x, b4[m].x, acc[k][m]);
          acc[k][m] = dot2(a4[k].y, b4[m].y, acc[k][m]);
          acc[k][m] = dot2(a4[k].z, b4[m].z, acc[k][m]);
          acc[k][m] = dot2(a4[k].w, b4[m].w, acc[k][m]);
        }
    }
  }
#pragma unroll
  for (int k = 0; k < 4; k++) {
    const int n = n0 + 16 * k + ry;
#pragma unroll
    for (int j = 0; j < 4; j++)
      dst[(size_t)n * 256 + (o0 >> 1) + 16 * j + px] =
          pack2(acc[k][2 * j], acc[k][2 * j + 1]);
  }
}

// Final layer: (2048,512) -> 6 classes.
__global__ void k_mlp3(const unsigned* __restrict__ y2h2,
                       const unsigned* __restrict__ wm3h2,
                       const float* __restrict__ bm3,
                       float* __restrict__ out) {
  const int nb = blockIdx.x;  // 32
  const int tid = threadIdx.x;
  __shared__ __align__(16) unsigned Ys[64 * 256];
  __shared__ __align__(16) unsigned Ws[6 * 256];
  for (int idx = tid; idx < 64 * 256; idx += 256)
    Ys[idx] = y2h2[(size_t)nb * 64 * 256 + idx];
  for (int idx = tid; idx < 6 * 256; idx += 256) Ws[idx] = wm3h2[idx];
  __syncthreads();
  for (int u = 0; u < 2; u++) {
    const int idx = tid + u * 256;
    if (idx < 384) {
      const int nl = idx / 6, c = idx - 6 * nl;
      float a0 = 0.f, a1 = 0.f;
#pragma unroll
      for (int kq = 0; kq < 64; kq++) {
        const uint4 y4 = *(const uint4*)&Ys[nl * 256 + 4 * kq];
        const uint4 w4 = *(const uint4*)&Ws[c * 256 + 4 * kq];
        a0 = dot2(y4.x, w4.x, a0);
        a1 = dot2(y4.y, w4.y, a1);
        a0 = dot2(y4.z, w4.z, a0);
        a1 = dot2(y4.w, w4.w, a1);
      }
      out[(size_t)(nb * 64 + nl) * 6 + c] = a0 + a1 + bm3[c];
    }
  }
}

// ---------------------------------------------------------------------------
extern "C" void kernel_launch(void* const* d_in, const int* in_sizes, int n_in,
                              void* d_out, int out_size, void* d_ws,
                              size_t ws_size, hipStream_t stream) {
  (void)in_sizes; (void)n_in; (void)out_size; (void)ws_size;
  const float* cnn  = (const float*)d_in[0];
  const float* gaze = (const float*)d_in[1];
  const float* W_lh = (const float*)d_in[2];
  const float* b_lh = (const float*)d_in[3];
  const float* W_cn = (const float*)d_in[4];
  const float* b_cn = (const float*)d_in[5];
  const float* w_wt = (const float*)d_in[6];
  const float* Wih  = (const float*)d_in[7];
  const float* Whh  = (const float*)d_in[8];
  const float* bih  = (const float*)d_in[9];
  const float* bhh  = (const float*)d_in[10];
  const float* Wh1  = (const float*)d_in[11];
  const float* bh1  = (const float*)d_in[12];
  const float* Wh2  = (const float*)d_in[13];
  const float* bh2  = (const float*)d_in[14];
  const float* Wc1  = (const float*)d_in[15];
  const float* bc1  = (const float*)d_in[16];
  const float* Wc2  = (const float*)d_in[17];
  const float* bc2  = (const float*)d_in[18];
  const float* Wm1  = (const float*)d_in[19];
  const float* bm1  = (const float*)d_in[20];
  const float* Wm2  = (const float*)d_in[21];
  const float* bm2  = (const float*)d_in[22];
  const float* Wm3  = (const float*)d_in[23];
  const float* bm3  = (const float*)d_in[24];
  float* out = (float*)d_out;

  unsigned* W = (unsigned*)d_ws;
  float* Wf = (float*)d_ws;
  // workspace offsets in dwords
  const size_t O_xg  = 0;                    // [31][64][1024] f32
  const size_t O_wv  = 2031616;              // [192][512]     u32
  const size_t O_wl  = O_wv + 98304;         // [1024][32]     u32
  const size_t O_HH  = O_wl + 32768;         // [33][64][256]  f32
  const size_t O_c0  = O_HH + 540672;        // [64][256]      f32
  const size_t O_Hl  = O_c0 + 16384;         // [32][64][128]  f32
  const size_t O_z   = O_Hl + 262144;        // [32][64][36]   f32
  const size_t O_fc  = O_z + 73728;          // [2048][512]    f32
  const size_t O_y1  = O_fc + 1048576;       // [2048][256]    u32 (h2)
  const size_t O_y2  = O_y1 + 524288;        // [2048][256]    u32 (h2)
  const size_t O_wcn = O_y2 + 524288;        // [128][128]     u32
  const size_t O_wlh = O_wcn + 16384;
  const size_t O_wm1 = O_wlh + 16384;        // [512][256]
  const size_t O_wm2 = O_wm1 + 131072;
  const size_t O_wm3 = O_wm2 + 131072;       // [6][256]

  float* xg  = Wf + O_xg;
  float* HH  = Wf + O_HH;
  float* c0f = Wf + O_c0;
  float* Hlf = Wf + O_Hl;
  float* zf  = Wf + O_z;
  float* fcf = Wf + O_fc;

  // --- prepacking (independent) ---
  k_pack_wv<<<512, 256, 0, stream>>>(Whh, W + O_wv, W + O_wl);
  k_packh2<<<64, 256, 0, stream>>>(W_cn, W + O_wcn, 16384);
  k_packh2<<<64, 256, 0, stream>>>(W_lh, W + O_wlh, 16384);
  k_packh2<<<512, 256, 0, stream>>>(Wm1, W + O_wm1, 131072);
  k_packh2<<<512, 256, 0, stream>>>(Wm2, W + O_wm2, 131072);
  k_packh2<<<6, 256, 0, stream>>>(Wm3, W + O_wm3, 1536);
  k_xg<<<7936, 256, 0, stream>>>(gaze, Wih, bih, bhh, xg);
  k_init<<<64, 256, 0, stream>>>(gaze, Wh1, bh1, Wh2, bh2, Wc1, bc1, Wc2, bc2,
                                 HH, c0f);
  // --- the sequential chain ---
  k_lstm<<<64, 512, 0, stream>>>(xg, W + O_wv, W + O_wl, c0f, HH);
  // --- batched attention ---
  k_hl<<<32, 256, 0, stream>>>(HH, W + O_wlh, b_lh, Hlf);
  k_att_z<<<576, 256, 0, stream>>>(cnn, W + O_wcn, b_cn, Hlf, w_wt, zf);
  k_att_sf<<<2048, 256, 0, stream>>>(cnn, zf, HH, fcf);
  // --- batched MLP ---
  k_mlp<0><<<128, 256, 0, stream>>>((const void*)fcf, W + O_wm1, bm1, W + O_y1);
  k_mlp<1><<<128, 256, 0, stream>>>((const void*)(W + O_y1), W + O_wm2, bm2, W + O_y2);
  k_mlp3<<<32, 256, 0, stream>>>(W + O_y2, W + O_wm3, bm3, out);
}

// Round 4
// 1199.373 us; speedup vs baseline: 4.7208x; 4.3634x over previous
//
#include <hip/hip_runtime.h>
#include <math.h>

// ---------------------------------------------------------------------------
// SpatialAttentionModel on MI355X.
// (1) init h0/c0, (2) precompute LSTM input projections, (3) ONE sequential
// LSTM chain (497 steps) recording h at frame boundaries, (4) batched
// attention, (5) batched 3-layer MLP.
// BS=64, T=32, GRID=36, FEAT=256, HID=256, PROJ=128, NCLS=6, MLP_IN=512.
// R4: k_lstm redesigned to FIT the 128-VGPR budget the backend insists on
// (R1-R3: three attribute variants all produced VGPR_Count=128 + spill).
// Now 1024 threads x 1 gate-row: 96 persistent weight dwords/thread
// (macro-unrolled loads - no dynamic-index path to scratch), 32 pairs/row in
// LDS. 16 waves = 4 waves/EU == the 128-reg occupancy target.
// ---------------------------------------------------------------------------

typedef _Float16 h2_t __attribute__((ext_vector_type(2)));

#if __has_builtin(__builtin_amdgcn_fdot2)
#define HAVE_FDOT2 1
#else
#define HAVE_FDOT2 0
#endif

__device__ __forceinline__ float dot2(unsigned w, unsigned h, float acc) {
#if HAVE_FDOT2
  return __builtin_amdgcn_fdot2(__builtin_bit_cast(h2_t, w),
                                __builtin_bit_cast(h2_t, h), acc, false);
#else
  h2_t a = __builtin_bit_cast(h2_t, w);
  h2_t b = __builtin_bit_cast(h2_t, h);
  return acc + (float)a[0] * (float)b[0] + (float)a[1] * (float)b[1];
#endif
}

__device__ __forceinline__ unsigned pack2(float a, float b) {
  h2_t p;
  p[0] = (_Float16)a;
  p[1] = (_Float16)b;
  return __builtin_bit_cast(unsigned, p);
}

__device__ __forceinline__ float sigmoid_f(float x) {
  return __builtin_amdgcn_rcpf(1.f + __expf(-x));
}
__device__ __forceinline__ float tanh_f(float x) {
  return 1.f - 2.f * __builtin_amdgcn_rcpf(1.f + __expf(2.f * x));
}

// ---------------------------------------------------------------------------
// Pack Whh into the LSTM kernel's two layouts:
//  wv_pack[m][tau] (m<96, tau<1024): VGPR-resident pair (32+m) of row tau.
//  wlds_pack[row][p] (p<32): pairs 0..31 of every row (read from LDS).
__global__ void k_pack_wv(const float* __restrict__ Whh,
                          unsigned* __restrict__ wv_pack,
                          unsigned* __restrict__ wlds_pack) {
  const int idx = blockIdx.x * 256 + threadIdx.x;  // < 131072
  if (idx < 98304) {
    const int m = idx >> 10, tau = idx & 1023;  // m < 96
    const int pair = 32 + m;
    wv_pack[idx] = pack2(Whh[tau * 256 + 2 * pair], Whh[tau * 256 + 2 * pair + 1]);
  } else {
    const int j = idx - 98304;  // < 32768
    const int row = j >> 5, pair = j & 31;
    wlds_pack[j] = pack2(Whh[row * 256 + 2 * pair], Whh[row * 256 + 2 * pair + 1]);
  }
}

// Generic f32 -> packed-f16-pair converter (contiguous rows, even cols).
__global__ void k_packh2(const float* __restrict__ src,
                         unsigned* __restrict__ dst, int n) {
  const int i = blockIdx.x * 256 + threadIdx.x;
  if (i < n) dst[i] = pack2(src[2 * i], src[2 * i + 1]);
}

// xg[t][b][j] = gaze[b,t,:]·Wih[j,:] + bih[j] + bhh[j],  t in [0,31)
__global__ void k_xg(const float* __restrict__ gaze,
                     const float* __restrict__ Wih,
                     const float* __restrict__ bih,
                     const float* __restrict__ bhh,
                     float* __restrict__ xg) {
  const int idx = blockIdx.x * 256 + threadIdx.x;
  if (idx >= 31 * 64 * 1024) return;
  const int j = idx & 1023;
  const int b = (idx >> 10) & 63;
  const int t = idx >> 16;
  const float* gz = gaze + (b * 32 + t) * 3;
  xg[idx] = gz[0] * Wih[j * 3 + 0] + gz[1] * Wih[j * 3 + 1] +
            gz[2] * Wih[j * 3 + 2] + bih[j] + bhh[j];
}

// h0/c0: h = tanh(tanh( tanh(mg@Wh1.T+bh1) @ Wh2.T + bh2 )), same for c.
__global__ void k_init(const float* __restrict__ gaze,
                       const float* __restrict__ Wh1, const float* __restrict__ bh1,
                       const float* __restrict__ Wh2, const float* __restrict__ bh2,
                       const float* __restrict__ Wc1, const float* __restrict__ bc1,
                       const float* __restrict__ Wc2, const float* __restrict__ bc2,
                       float* __restrict__ HH, float* __restrict__ c0) {
  const int b = blockIdx.x;
  const int tid = threadIdx.x;  // 256
  __shared__ float mg[3];
  __shared__ float t1h[256], t1c[256];
  if (tid < 3) {
    float s = 0.f;
    for (int t = 0; t < 32; t++) s += gaze[(b * 32 + t) * 3 + tid];
    mg[tid] = s * (1.f / 32.f);
  }
  __syncthreads();
  {
    float a = mg[0] * Wh1[tid * 3 + 0] + mg[1] * Wh1[tid * 3 + 1] +
              mg[2] * Wh1[tid * 3 + 2] + bh1[tid];
    t1h[tid] = tanhf(a);
    float c = mg[0] * Wc1[tid * 3 + 0] + mg[1] * Wc1[tid * 3 + 1] +
              mg[2] * Wc1[tid * 3 + 2] + bc1[tid];
    t1c[tid] = tanhf(c);
  }
  __syncthreads();
  float s1 = bh2[tid], s2 = bc2[tid];
  for (int k = 0; k < 256; k++) {
    s1 += t1h[k] * Wh2[tid * 256 + k];
    s2 += t1c[k] * Wc2[tid * 256 + k];
  }
  HH[b * 256 + tid] = tanhf(tanhf(s1));  // HH[0][b][k]
  c0[b * 256 + tid] = tanhf(tanhf(s2));
}

// ---------------------------------------------------------------------------
// The sequential LSTM chain. One block per batch element. 1024 threads;
// thread tau owns gate row tau. f16 weights: pairs 32..127 in VGPRs
// (96 dwords, macro-unrolled loads), pairs 0..31 in LDS (stride-36 rows,
// 0 bank conflicts measured). h broadcast from LDS as packed-f16 uint4;
// h written back as ds_write_b16. 16 waves = 4 waves/EU -> fits the
// backend's 128-VGPR allocation target without spilling.
__global__ __launch_bounds__(1024) void k_lstm(
    const float* __restrict__ xg, const unsigned* __restrict__ wv_pack,
    const unsigned* __restrict__ wlds_pack, const float* __restrict__ c0,
    float* __restrict__ HH) {
  const int b = blockIdx.x;
  const int tid = threadIdx.x;  // gate row tau
  __shared__ __align__(16) unsigned wlds[1024 * 36];  // 147456 B
  __shared__ float actl[1024];
  __shared__ __align__(16) unsigned h2l[128];

  for (int i = tid; i < 1024 * 32; i += 1024) {
    const int row = i >> 5, p = i & 31;
    wlds[row * 36 + p] = wlds_pack[i];
  }
  unsigned wv[96];
  {
    const unsigned* wvp = wv_pack + tid;
#define LD1(m) wv[(m)] = wvp[(m) * 1024];
#define LD8(m) LD1(m) LD1((m) + 1) LD1((m) + 2) LD1((m) + 3) \
               LD1((m) + 4) LD1((m) + 5) LD1((m) + 6) LD1((m) + 7)
    LD8(0) LD8(8) LD8(16) LD8(24) LD8(32) LD8(40)
    LD8(48) LD8(56) LD8(64) LD8(72) LD8(80) LD8(88)
#undef LD1
#undef LD8
  }

  float cst = (tid < 256) ? c0[b * 256 + tid] : 0.f;
  if (tid < 256) ((_Float16*)h2l)[tid] = (_Float16)HH[b * 256 + tid];
  __syncthreads();

  const unsigned* wA = &wlds[tid * 36];
  const bool is_g = (tid >= 512) & (tid < 768);  // wave-uniform
  float hval = 0.f;

  for (int frame = 0; frame < 32; frame++) {
    const int L = frame ? frame : 1;
    for (int t = 0; t < L; t++) {
      const float xgv = xg[(t * 64 + b) * 1024 + tid];
      float ga0 = 0.f, ga1 = 0.f;
      // pairs 0..31 from LDS weights
#pragma unroll
      for (int q = 0; q < 8; q++) {
        const uint4 h4 = *(const uint4*)&h2l[4 * q];
        const uint4 a4 = *(const uint4*)&wA[4 * q];
        if ((q & 1) == 0) {
          ga0 = dot2(a4.x, h4.x, ga0);
          ga0 = dot2(a4.y, h4.y, ga0);
          ga0 = dot2(a4.z, h4.z, ga0);
          ga0 = dot2(a4.w, h4.w, ga0);
        } else {
          ga1 = dot2(a4.x, h4.x, ga1);
          ga1 = dot2(a4.y, h4.y, ga1);
          ga1 = dot2(a4.z, h4.z, ga1);
          ga1 = dot2(a4.w, h4.w, ga1);
        }
      }
      // pairs 32..127 from VGPR weights
#pragma unroll
      for (int q = 0; q < 24; q++) {
        const uint4 h4 = *(const uint4*)&h2l[32 + 4 * q];
        if ((q & 1) == 0) {
          ga0 = dot2(wv[4 * q + 0], h4.x, ga0);
          ga0 = dot2(wv[4 * q + 1], h4.y, ga0);
          ga0 = dot2(wv[4 * q + 2], h4.z, ga0);
          ga0 = dot2(wv[4 * q + 3], h4.w, ga0);
        } else {
          ga1 = dot2(wv[4 * q + 0], h4.x, ga1);
          ga1 = dot2(wv[4 * q + 1], h4.y, ga1);
          ga1 = dot2(wv[4 * q + 2], h4.z, ga1);
          ga1 = dot2(wv[4 * q + 3], h4.w, ga1);
        }
      }
      const float g = ga0 + ga1 + xgv;
      const float act = is_g ? tanh_f(g) : sigmoid_f(g);
      actl[tid] = act;
      __syncthreads();  // B1: h2l reads done; acts visible
      if (tid < 256) {
        const float i_ = actl[tid];
        const float f_ = actl[256 + tid];
        const float g_ = actl[512 + tid];
        const float o_ = actl[768 + tid];
        cst = f_ * cst + i_ * g_;
        hval = o_ * tanh_f(cst);
        ((_Float16*)h2l)[tid] = (_Float16)hval;
      }
      __syncthreads();  // B2: h2l ready for next step
    }
    if (tid < 256) HH[((frame + 1) * 64 + b) * 256 + tid] = hval;
  }
}

// Hl[i][b][p] = HH[i][b]·W_lh[p] + b_lh[p]. One block per frame.
__global__ void k_hl(const float* __restrict__ HH,
                     const unsigned* __restrict__ wlh_h2,
                     const float* __restrict__ blh, float* __restrict__ Hl) {
  const int i = blockIdx.x;
  const int tid = threadIdx.x;  // 256
  __shared__ __align__(16) unsigned Ah[64 * 132];
  __shared__ __align__(16) unsigned Bh[128 * 132];
  for (int idx = tid; idx < 64 * 128; idx += 256) {
    const int r = idx >> 7, kp = idx & 127;
    const float* s = HH + ((size_t)(i * 64 + r)) * 256 + 2 * kp;
    Ah[r * 132 + kp] = pack2(s[0], s[1]);
  }
  for (int idx = tid; idx < 128 * 128; idx += 256) {
    const int o = idx >> 7, kp = idx & 127;
    Bh[o * 132 + kp] = wlh_h2[o * 128 + kp];
  }
  __syncthreads();
  const int ry = tid >> 4, px = tid & 15;
  float acc[4][8];
#pragma unroll
  for (int k = 0; k < 4; k++)
#pragma unroll
    for (int j = 0; j < 8; j++) acc[k][j] = 0.f;
  for (int kb = 0; kb < 32; kb++) {
    uint4 a4[4], b4[8];
#pragma unroll
    for (int k = 0; k < 4; k++) a4[k] = *(const uint4*)&Ah[(16 * k + ry) * 132 + 4 * kb];
#pragma unroll
    for (int j = 0; j < 8; j++) b4[j] = *(const uint4*)&Bh[(16 * j + px) * 132 + 4 * kb];
#pragma unroll
    for (int k = 0; k < 4; k++)
#pragma unroll
      for (int j = 0; j < 8; j++) {
        acc[k][j] = dot2(a4[k].x, b4[j].x, acc[k][j]);
        acc[k][j] = dot2(a4[k].y, b4[j].y, acc[k][j]);
        acc[k][j] = dot2(a4[k].z, b4[j].z, acc[k][j]);
        acc[k][j] = dot2(a4[k].w, b4[j].w, acc[k][j]);
      }
  }
#pragma unroll
  for (int k = 0; k < 4; k++)
#pragma unroll
    for (int j = 0; j < 8; j++)
      Hl[(i * 64 + 16 * k + ry) * 128 + 16 * j + px] = acc[k][j] + blh[16 * j + px];
}

// Fused Vp GEMM + z. Rows = flattened (b,g) within frame i (2304 rows, tiles
// of 128). z[b,g] = sum_p w[p]*tanh(Hl[b,p] + Vp[b,g,p]).
__global__ void k_att_z(const float* __restrict__ cnn,
                        const unsigned* __restrict__ wcn_h2,
                        const float* __restrict__ bcn,
                        const float* __restrict__ Hl,
                        const float* __restrict__ wwt,
                        float* __restrict__ zbuf) {
  const int bid = blockIdx.x;  // 576 = 32 frames * 18 row tiles
  const int i = bid / 18, rt = bid - 18 * i;
  const int tid = threadIdx.x;  // 256
  const int r0 = rt * 128;
  __shared__ __align__(16) unsigned As[128 * 132];
  __shared__ __align__(16) unsigned Bs[128 * 132];
  __shared__ float zpart[128 * 16];
  __shared__ float Hls[5 * 128];
  __shared__ float wws[128];
  __shared__ float bcs[128];

  for (int idx = tid; idx < 128 * 128; idx += 256) {
    const int r = idx >> 7, kp = idx & 127;
    const int R = r0 + r;
    const int b = R / 36, g = R - b * 36;
    const float* src = cnn + (((size_t)b * 32 + i) * 36 + g) * 256 + 2 * kp;
    As[r * 132 + kp] = pack2(src[0], src[1]);
  }
  for (int idx = tid; idx < 128 * 128; idx += 256) {
    const int o = idx >> 7, kp = idx & 127;
    Bs[o * 132 + kp] = wcn_h2[o * 128 + kp];
  }
  const int bmin = r0 / 36;
  for (int idx = tid; idx < 5 * 128; idx += 256) {
    const int bb = bmin + (idx >> 7);
    if (bb < 64) Hls[idx] = Hl[(i * 64 + bb) * 128 + (idx & 127)];
  }
  if (tid < 128) {
    wws[tid] = wwt[tid];
    bcs[tid] = bcn[tid];
  }
  __syncthreads();

  const int ry = tid >> 4, px = tid & 15;
  float acc[8][8];
#pragma unroll
  for (int k = 0; k < 8; k++)
#pragma unroll
    for (int j = 0; j < 8; j++) acc[k][j] = bcs[16 * j + px];
  for (int kb = 0; kb < 32; kb++) {
    uint4 a4[8], b4[8];
#pragma unroll
    for (int k = 0; k < 8; k++) a4[k] = *(const uint4*)&As[(16 * k + ry) * 132 + 4 * kb];
#pragma unroll
    for (int j = 0; j < 8; j++) b4[j] = *(const uint4*)&Bs[(16 * j + px) * 132 + 4 * kb];
#pragma unroll
    for (int k = 0; k < 8; k++)
#pragma unroll
      for (int j = 0; j < 8; j++) {
        acc[k][j] = dot2(a4[k].x, b4[j].x, acc[k][j]);
        acc[k][j] = dot2(a4[k].y, b4[j].y, acc[k][j]);
        acc[k][j] = dot2(a4[k].z, b4[j].z, acc[k][j]);
        acc[k][j] = dot2(a4[k].w, b4[j].w, acc[k][j]);
      }
  }
#pragma unroll
  for (int k = 0; k < 8; k++) {
    const int r = 16 * k + ry;
    const int R = r0 + r;
    const int b = R / 36;
    const float* HlRow = &Hls[(b - bmin) * 128];
    float zp = 0.f;
#pragma unroll
    for (int j = 0; j < 8; j++) {
      const int po = 16 * j + px;
      zp += wws[po] * tanh_f(HlRow[po] + acc[k][j]);
    }
    zpart[r * 16 + px] = zp;
  }
  __syncthreads();
  if (tid < 128) {
    float z = 0.f;
#pragma unroll
    for (int x = 0; x < 16; x++) z += zpart[tid * 16 + x];
    const int R = r0 + tid;
    const int b = R / 36, g = R - b * 36;
    zbuf[(i * 64 + b) * 36 + g] = z;
  }
}

// Scrambled softmax + weighted V sum; builds fc = [spatial_feat | h_next].
__global__ void k_att_sf(const float* __restrict__ cnn,
                         const float* __restrict__ zbuf,
                         const float* __restrict__ HH,
                         float* __restrict__ fc) {
  const int bid = blockIdx.x;  // 2048 = i*64 + b
  const int i = bid >> 6, b = bid & 63;
  const int tid = threadIdx.x;  // 256
  __shared__ float zl[36];
  __shared__ float el[40];
  __shared__ float red[1];
  if (tid < 36) {
    const int idx = b * 36 + tid;  // scramble: z.T.reshape(64,36)
    zl[tid] = zbuf[(i * 64 + (idx & 63)) * 36 + (idx >> 6)];
  }
  __syncthreads();
  if (tid == 0) {
    float m = zl[0];
    for (int g = 1; g < 36; g++) m = fmaxf(m, zl[g]);
    float s = 0.f;
    for (int g = 0; g < 36; g++) {
      const float e = __expf(zl[g] - m);
      el[g] = e;
      s += e;
    }
    red[0] = 1.f / s;
  }
  __syncthreads();
  const float inv = red[0];
  float accv = 0.f;
  const float* Vb = cnn + (((size_t)b * 32 + i) * 36) * 256 + tid;
#pragma unroll 4
  for (int g = 0; g < 36; g++) accv += el[g] * Vb[g * 256];
  fc[(size_t)bid * 512 + tid] = accv * inv;
  fc[(size_t)bid * 512 + 256 + tid] = HH[((i + 1) * 64 + b) * 256 + tid];
}

// MLP layers 1/2: (2048,512)@(512,512)+b, output packed f16 pairs.
template <int SRCMODE>  // 0: f32 src (fc), 1: packed-h2 src
__global__ void k_mlp(const void* __restrict__ src,
                      const unsigned* __restrict__ wh2,
                      const float* __restrict__ bias,
                      unsigned* __restrict__ dst) {
  const int bid = blockIdx.x;  // 128 = 32 n-tiles * 4 o-tiles
  const int nb = bid >> 2, ob = bid & 3;
  const int n0 = nb * 64, o0 = ob * 128;
  const int tid = threadIdx.x;
  __shared__ __align__(16) unsigned As[64 * 132];
  __shared__ __align__(16) unsigned Bs[128 * 132];
  const int ry = tid >> 4, px = tid & 15;
  float acc[4][8];
#pragma unroll
  for (int k = 0; k < 4; k++)
#pragma unroll
    for (int m = 0; m < 8; m++)
      acc[k][m] = bias[o0 + 32 * (m >> 1) + 2 * px + (m & 1)];
  for (int kc = 0; kc < 2; kc++) {
    __syncthreads();
    for (int idx = tid; idx < 64 * 128; idx += 256) {
      const int r = idx >> 7, kp = idx & 127;
      if (SRCMODE == 0) {
        const float* s = (const float*)src + ((size_t)(n0 + r)) * 512 + kc * 256 + 2 * kp;
        As[r * 132 + kp] = pack2(s[0], s[1]);
      } else {
        As[r * 132 + kp] = ((const unsigned*)src)[((size_t)(n0 + r)) * 256 + kc * 128 + kp];
      }
    }
    for (int idx = tid; idx < 128 * 128; idx += 256) {
      const int o = idx >> 7, kp = idx & 127;
      Bs[o * 132 + kp] = wh2[((size_t)(o0 + o)) * 256 + kc * 128 + kp];
    }
    __syncthreads();
    for (int kb = 0; kb < 32; kb++) {
      uint4 a4[4], b4[8];
#pragma unroll
      for (int k = 0; k < 4; k++)
        a4[k] = *(const uint4*)&As[(16 * k + ry) * 132 + 4 * kb];
#pragma unroll
      for (int m = 0; m < 8; m++)
        b4[m] = *(const uint4*)&Bs[(32 * (m >> 1) + 2 * px + (m & 1)) * 132 + 4 * kb];
#pragma unroll
      for (int k = 0; k < 4; k++)
#pragma unroll
        for (int m = 0; m < 8; m++) {
          acc[k][m] = dot2(a4[k].x, b4[m].x, acc[k][m]);
          acc[k][m] = dot2(a4[k].y, b4[m].y, acc[k][m]);
          acc[k][m] = dot2(a4[k].z, b4[m].z, acc[k][m]);
          acc[k][m] = dot2(a4[k].w, b4[m].w, acc[k][m]);
        }
    }
  }
#pragma unroll
  for (int k = 0; k < 4; k++) {
    const int n = n0 + 16 * k + ry;
#pragma unroll
    for (int j = 0; j < 4; j++)
      dst[(size_t)n * 256 + (o0 >> 1) + 16 * j + px] =
          pack2(acc[k][2 * j], acc[k][2 * j + 1]);
  }
}

// Final layer: (2048,512) -> 6 classes.
__global__ void k_mlp3(const unsigned* __restrict__ y2h2,
                       const unsigned* __restrict__ wm3h2,
                       const float* __restrict__ bm3,
                       float* __restrict__ out) {
  const int nb = blockIdx.x;  // 32
  const int tid = threadIdx.x;
  __shared__ __align__(16) unsigned Ys[64 * 256];
  __shared__ __align__(16) unsigned Ws[6 * 256];
  for (int idx = tid; idx < 64 * 256; idx += 256)
    Ys[idx] = y2h2[(size_t)nb * 64 * 256 + idx];
  for (int idx = tid; idx < 6 * 256; idx += 256) Ws[idx] = wm3h2[idx];
  __syncthreads();
  for (int u = 0; u < 2; u++) {
    const int idx = tid + u * 256;
    if (idx < 384) {
      const int nl = idx / 6, c = idx - 6 * nl;
      float a0 = 0.f, a1 = 0.f;
#pragma unroll
      for (int kq = 0; kq < 64; kq++) {
        const uint4 y4 = *(const uint4*)&Ys[nl * 256 + 4 * kq];
        const uint4 w4 = *(const uint4*)&Ws[c * 256 + 4 * kq];
        a0 = dot2(y4.x, w4.x, a0);
        a1 = dot2(y4.y, w4.y, a1);
        a0 = dot2(y4.z, w4.z, a0);
        a1 = dot2(y4.w, w4.w, a1);
      }
      out[(size_t)(nb * 64 + nl) * 6 + c] = a0 + a1 + bm3[c];
    }
  }
}

// ---------------------------------------------------------------------------
extern "C" void kernel_launch(void* const* d_in, const int* in_sizes, int n_in,
                              void* d_out, int out_size, void* d_ws,
                              size_t ws_size, hipStream_t stream) {
  (void)in_sizes; (void)n_in; (void)out_size; (void)ws_size;
  const float* cnn  = (const float*)d_in[0];
  const float* gaze = (const float*)d_in[1];
  const float* W_lh = (const float*)d_in[2];
  const float* b_lh = (const float*)d_in[3];
  const float* W_cn = (const float*)d_in[4];
  const float* b_cn = (const float*)d_in[5];
  const float* w_wt = (const float*)d_in[6];
  const float* Wih  = (const float*)d_in[7];
  const float* Whh  = (const float*)d_in[8];
  const float* bih  = (const float*)d_in[9];
  const float* bhh  = (const float*)d_in[10];
  const float* Wh1  = (const float*)d_in[11];
  const float* bh1  = (const float*)d_in[12];
  const float* Wh2  = (const float*)d_in[13];
  const float* bh2  = (const float*)d_in[14];
  const float* Wc1  = (const float*)d_in[15];
  const float* bc1  = (const float*)d_in[16];
  const float* Wc2  = (const float*)d_in[17];
  const float* bc2  = (const float*)d_in[18];
  const float* Wm1  = (const float*)d_in[19];
  const float* bm1  = (const float*)d_in[20];
  const float* Wm2  = (const float*)d_in[21];
  const float* bm2  = (const float*)d_in[22];
  const float* Wm3  = (const float*)d_in[23];
  const float* bm3  = (const float*)d_in[24];
  float* out = (float*)d_out;

  unsigned* W = (unsigned*)d_ws;
  float* Wf = (float*)d_ws;
  // workspace offsets in dwords
  const size_t O_xg  = 0;                    // [31][64][1024] f32
  const size_t O_wv  = 2031616;              // [96][1024]     u32
  const size_t O_wl  = O_wv + 98304;         // [1024][32]     u32
  const size_t O_HH  = O_wl + 32768;         // [33][64][256]  f32
  const size_t O_c0  = O_HH + 540672;        // [64][256]      f32
  const size_t O_Hl  = O_c0 + 16384;         // [32][64][128]  f32
  const size_t O_z   = O_Hl + 262144;        // [32][64][36]   f32
  const size_t O_fc  = O_z + 73728;          // [2048][512]    f32
  const size_t O_y1  = O_fc + 1048576;       // [2048][256]    u32 (h2)
  const size_t O_y2  = O_y1 + 524288;        // [2048][256]    u32 (h2)
  const size_t O_wcn = O_y2 + 524288;        // [128][128]     u32
  const size_t O_wlh = O_wcn + 16384;
  const size_t O_wm1 = O_wlh + 16384;        // [512][256]
  const size_t O_wm2 = O_wm1 + 131072;
  const size_t O_wm3 = O_wm2 + 131072;       // [6][256]

  float* xg  = Wf + O_xg;
  float* HH  = Wf + O_HH;
  float* c0f = Wf + O_c0;
  float* Hlf = Wf + O_Hl;
  float* zf  = Wf + O_z;
  float* fcf = Wf + O_fc;

  // --- prepacking (independent) ---
  k_pack_wv<<<512, 256, 0, stream>>>(Whh, W + O_wv, W + O_wl);
  k_packh2<<<64, 256, 0, stream>>>(W_cn, W + O_wcn, 16384);
  k_packh2<<<64, 256, 0, stream>>>(W_lh, W + O_wlh, 16384);
  k_packh2<<<512, 256, 0, stream>>>(Wm1, W + O_wm1, 131072);
  k_packh2<<<512, 256, 0, stream>>>(Wm2, W + O_wm2, 131072);
  k_packh2<<<6, 256, 0, stream>>>(Wm3, W + O_wm3, 1536);
  k_xg<<<7936, 256, 0, stream>>>(gaze, Wih, bih, bhh, xg);
  k_init<<<64, 256, 0, stream>>>(gaze, Wh1, bh1, Wh2, bh2, Wc1, bc1, Wc2, bc2,
                                 HH, c0f);
  // --- the sequential chain ---
  k_lstm<<<64, 1024, 0, stream>>>(xg, W + O_wv, W + O_wl, c0f, HH);
  // --- batched attention ---
  k_hl<<<32, 256, 0, stream>>>(HH, W + O_wlh, b_lh, Hlf);
  k_att_z<<<576, 256, 0, stream>>>(cnn, W + O_wcn, b_cn, Hlf, w_wt, zf);
  k_att_sf<<<2048, 256, 0, stream>>>(cnn, zf, HH, fcf);
  // --- batched MLP ---
  k_mlp<0><<<128, 256, 0, stream>>>((const void*)fcf, W + O_wm1, bm1, W + O_y1);
  k_mlp<1><<<128, 256, 0, stream>>>((const void*)(W + O_y1), W + O_wm2, bm2, W + O_y2);
  k_mlp3<<<32, 256, 0, stream>>>(W + O_y2, W + O_wm3, bm3, out);
}

// Round 6
// 1196.739 us; speedup vs baseline: 4.7312x; 1.0022x over previous
//
#include <hip/hip_runtime.h>
#include <math.h>

// ---------------------------------------------------------------------------
// SpatialAttentionModel on MI355X.
// (1) init h0/c0, (2) precompute LSTM input projections, (3) ONE sequential
// LSTM chain (497 steps) recording h at frame boundaries, (4) batched
// attention, (5) batched 3-layer MLP.
// BS=64, T=32, GRID=36, FEAT=256, HID=256, PROJ=128, NCLS=6, MLP_IN=512.
// R6: R5's uint4 "+v" pin hit a backend limitation (tied indirect register
// inputs). Same mechanism, scalar operands: load 24 uint4 quads, destructure
// into 96 named unsigned scalars, pin with 4 asm volatile statements of 24
// scalar "+v" ties. Load-sinking (R4: VGPR_Count=64, per-step L2 re-fetch)
// cannot rematerialize past an asm def.
// ---------------------------------------------------------------------------

typedef _Float16 h2_t __attribute__((ext_vector_type(2)));

#if __has_builtin(__builtin_amdgcn_fdot2)
#define HAVE_FDOT2 1
#else
#define HAVE_FDOT2 0
#endif

__device__ __forceinline__ float dot2(unsigned w, unsigned h, float acc) {
#if HAVE_FDOT2
  return __builtin_amdgcn_fdot2(__builtin_bit_cast(h2_t, w),
                                __builtin_bit_cast(h2_t, h), acc, false);
#else
  h2_t a = __builtin_bit_cast(h2_t, w);
  h2_t b = __builtin_bit_cast(h2_t, h);
  return acc + (float)a[0] * (float)b[0] + (float)a[1] * (float)b[1];
#endif
}

__device__ __forceinline__ unsigned pack2(float a, float b) {
  h2_t p;
  p[0] = (_Float16)a;
  p[1] = (_Float16)b;
  return __builtin_bit_cast(unsigned, p);
}

__device__ __forceinline__ float sigmoid_f(float x) {
  return __builtin_amdgcn_rcpf(1.f + __expf(-x));
}
__device__ __forceinline__ float tanh_f(float x) {
  return 1.f - 2.f * __builtin_amdgcn_rcpf(1.f + __expf(2.f * x));
}

// ---------------------------------------------------------------------------
// Pack Whh into the LSTM kernel's two layouts:
//  wv_pack (uint4 view): [24][1024] quads; quad (m,tau) = pairs 32+4m..32+4m+3
//  of gate row tau -> one 16B load per quad per thread.
//  wlds_pack[row][p] (p<32): pairs 0..31 of every row (read from LDS).
__global__ void k_pack_wv(const float* __restrict__ Whh,
                          unsigned* __restrict__ wv_pack,
                          unsigned* __restrict__ wlds_pack) {
  const int idx = blockIdx.x * 256 + threadIdx.x;  // < 131072
  if (idx < 98304) {
    const int quad = idx >> 2, j = idx & 3;
    const int m = quad >> 10, tau = quad & 1023;  // m < 24
    const int pair = 32 + 4 * m + j;
    wv_pack[idx] = pack2(Whh[tau * 256 + 2 * pair], Whh[tau * 256 + 2 * pair + 1]);
  } else {
    const int j = idx - 98304;  // < 32768
    const int row = j >> 5, pair = j & 31;
    wlds_pack[j] = pack2(Whh[row * 256 + 2 * pair], Whh[row * 256 + 2 * pair + 1]);
  }
}

// Generic f32 -> packed-f16-pair converter (contiguous rows, even cols).
__global__ void k_packh2(const float* __restrict__ src,
                         unsigned* __restrict__ dst, int n) {
  const int i = blockIdx.x * 256 + threadIdx.x;
  if (i < n) dst[i] = pack2(src[2 * i], src[2 * i + 1]);
}

// xg[t][b][j] = gaze[b,t,:]·Wih[j,:] + bih[j] + bhh[j],  t in [0,31)
__global__ void k_xg(const float* __restrict__ gaze,
                     const float* __restrict__ Wih,
                     const float* __restrict__ bih,
                     const float* __restrict__ bhh,
                     float* __restrict__ xg) {
  const int idx = blockIdx.x * 256 + threadIdx.x;
  if (idx >= 31 * 64 * 1024) return;
  const int j = idx & 1023;
  const int b = (idx >> 10) & 63;
  const int t = idx >> 16;
  const float* gz = gaze + (b * 32 + t) * 3;
  xg[idx] = gz[0] * Wih[j * 3 + 0] + gz[1] * Wih[j * 3 + 1] +
            gz[2] * Wih[j * 3 + 2] + bih[j] + bhh[j];
}

// h0/c0: h = tanh(tanh( tanh(mg@Wh1.T+bh1) @ Wh2.T + bh2 )), same for c.
__global__ void k_init(const float* __restrict__ gaze,
                       const float* __restrict__ Wh1, const float* __restrict__ bh1,
                       const float* __restrict__ Wh2, const float* __restrict__ bh2,
                       const float* __restrict__ Wc1, const float* __restrict__ bc1,
                       const float* __restrict__ Wc2, const float* __restrict__ bc2,
                       float* __restrict__ HH, float* __restrict__ c0) {
  const int b = blockIdx.x;
  const int tid = threadIdx.x;  // 256
  __shared__ float mg[3];
  __shared__ float t1h[256], t1c[256];
  if (tid < 3) {
    float s = 0.f;
    for (int t = 0; t < 32; t++) s += gaze[(b * 32 + t) * 3 + tid];
    mg[tid] = s * (1.f / 32.f);
  }
  __syncthreads();
  {
    float a = mg[0] * Wh1[tid * 3 + 0] + mg[1] * Wh1[tid * 3 + 1] +
              mg[2] * Wh1[tid * 3 + 2] + bh1[tid];
    t1h[tid] = tanhf(a);
    float c = mg[0] * Wc1[tid * 3 + 0] + mg[1] * Wc1[tid * 3 + 1] +
              mg[2] * Wc1[tid * 3 + 2] + bc1[tid];
    t1c[tid] = tanhf(c);
  }
  __syncthreads();
  float s1 = bh2[tid], s2 = bc2[tid];
  for (int k = 0; k < 256; k++) {
    s1 += t1h[k] * Wh2[tid * 256 + k];
    s2 += t1c[k] * Wc2[tid * 256 + k];
  }
  HH[b * 256 + tid] = tanhf(tanhf(s1));  // HH[0][b][k]
  c0[b * 256 + tid] = tanhf(tanhf(s2));
}

// ---------------------------------------------------------------------------
// The sequential LSTM chain. One block per batch element. 1024 threads;
// thread tau owns gate row tau. f16 weights: pairs 32..127 live in 96 named
// scalar VGPRs, PINNED via scalar "+v" asm ties (R5's uint4 tie is a backend
// limitation). Pairs 0..31 in LDS (stride-36 rows, 0 bank conflicts).
// h broadcast from LDS as packed-f16 uint4; h written back as ds_write_b16.
__global__ __launch_bounds__(1024) void k_lstm(
    const float* __restrict__ xg, const unsigned* __restrict__ wv_pack,
    const unsigned* __restrict__ wlds_pack, const float* __restrict__ c0,
    float* __restrict__ HH) {
  const int b = blockIdx.x;
  const int tid = threadIdx.x;  // gate row tau
  __shared__ __align__(16) unsigned wlds[1024 * 36];  // 147456 B
  __shared__ float actl[1024];
  __shared__ __align__(16) unsigned h2l[128];

  for (int i = tid; i < 1024 * 32; i += 1024) {
    const int row = i >> 5, p = i & 31;
    wlds[row * 36 + p] = wlds_pack[i];
  }

  // 96 persistent weight dwords: 24 dwordx4 loads -> 96 named scalars.
  const uint4* wqp = (const uint4*)wv_pack + tid;
#define DECLQ(M)                                                   \
  const uint4 q##M = wqp[(M) * 1024];                              \
  unsigned w##M##x = q##M.x, w##M##y = q##M.y, w##M##z = q##M.z,   \
           w##M##w = q##M.w;
  DECLQ(0) DECLQ(1) DECLQ(2) DECLQ(3) DECLQ(4) DECLQ(5)
  DECLQ(6) DECLQ(7) DECLQ(8) DECLQ(9) DECLQ(10) DECLQ(11)
  DECLQ(12) DECLQ(13) DECLQ(14) DECLQ(15) DECLQ(16) DECLQ(17)
  DECLQ(18) DECLQ(19) DECLQ(20) DECLQ(21) DECLQ(22) DECLQ(23)
#undef DECLQ
  // Pin: after these asm defs the values are opaque - the load-sinking /
  // rematerialization passes cannot turn loop uses back into L2 loads.
#define PIN4(M) "+v"(w##M##x), "+v"(w##M##y), "+v"(w##M##z), "+v"(w##M##w)
  asm volatile("" : PIN4(0), PIN4(1), PIN4(2), PIN4(3), PIN4(4), PIN4(5));
  asm volatile("" : PIN4(6), PIN4(7), PIN4(8), PIN4(9), PIN4(10), PIN4(11));
  asm volatile("" : PIN4(12), PIN4(13), PIN4(14), PIN4(15), PIN4(16), PIN4(17));
  asm volatile("" : PIN4(18), PIN4(19), PIN4(20), PIN4(21), PIN4(22), PIN4(23));
#undef PIN4

  float cst = (tid < 256) ? c0[b * 256 + tid] : 0.f;
  if (tid < 256) ((_Float16*)h2l)[tid] = (_Float16)HH[b * 256 + tid];
  __syncthreads();

  const unsigned* wA = &wlds[tid * 36];
  const bool is_g = (tid >= 512) & (tid < 768);  // wave-uniform
  float hval = 0.f;

  for (int frame = 0; frame < 32; frame++) {
    const int L = frame ? frame : 1;
    for (int t = 0; t < L; t++) {
      const float xgv = xg[(t * 64 + b) * 1024 + tid];
      float ga0 = 0.f, ga1 = 0.f;
      // pairs 0..31 from LDS weights
#pragma unroll
      for (int q = 0; q < 8; q++) {
        const uint4 h4 = *(const uint4*)&h2l[4 * q];
        const uint4 a4 = *(const uint4*)&wA[4 * q];
        if ((q & 1) == 0) {
          ga0 = dot2(a4.x, h4.x, ga0);
          ga0 = dot2(a4.y, h4.y, ga0);
          ga0 = dot2(a4.z, h4.z, ga0);
          ga0 = dot2(a4.w, h4.w, ga0);
        } else {
          ga1 = dot2(a4.x, h4.x, ga1);
          ga1 = dot2(a4.y, h4.y, ga1);
          ga1 = dot2(a4.z, h4.z, ga1);
          ga1 = dot2(a4.w, h4.w, ga1);
        }
      }
      // pairs 32..127 from the pinned scalars
#define DOT4(M, ACC)                                    \
  {                                                     \
    const uint4 h4 = *(const uint4*)&h2l[32 + 4 * (M)]; \
    ACC = dot2(w##M##x, h4.x, ACC);                     \
    ACC = dot2(w##M##y, h4.y, ACC);                     \
    ACC = dot2(w##M##z, h4.z, ACC);                     \
    ACC = dot2(w##M##w, h4.w, ACC);                     \
  }
      DOT4(0, ga0) DOT4(1, ga1) DOT4(2, ga0) DOT4(3, ga1)
      DOT4(4, ga0) DOT4(5, ga1) DOT4(6, ga0) DOT4(7, ga1)
      DOT4(8, ga0) DOT4(9, ga1) DOT4(10, ga0) DOT4(11, ga1)
      DOT4(12, ga0) DOT4(13, ga1) DOT4(14, ga0) DOT4(15, ga1)
      DOT4(16, ga0) DOT4(17, ga1) DOT4(18, ga0) DOT4(19, ga1)
      DOT4(20, ga0) DOT4(21, ga1) DOT4(22, ga0) DOT4(23, ga1)
#undef DOT4
      const float g = ga0 + ga1 + xgv;
      const float act = is_g ? tanh_f(g) : sigmoid_f(g);
      actl[tid] = act;
      __syncthreads();  // B1: h2l reads done; acts visible
      if (tid < 256) {
        const float i_ = actl[tid];
        const float f_ = actl[256 + tid];
        const float g_ = actl[512 + tid];
        const float o_ = actl[768 + tid];
        cst = f_ * cst + i_ * g_;
        hval = o_ * tanh_f(cst);
        ((_Float16*)h2l)[tid] = (_Float16)hval;
      }
      __syncthreads();  // B2: h2l ready for next step
    }
    if (tid < 256) HH[((frame + 1) * 64 + b) * 256 + tid] = hval;
  }
}

// Hl[i][b][p] = HH[i][b]·W_lh[p] + b_lh[p]. One block per frame.
__global__ void k_hl(const float* __restrict__ HH,
                     const unsigned* __restrict__ wlh_h2,
                     const float* __restrict__ blh, float* __restrict__ Hl) {
  const int i = blockIdx.x;
  const int tid = threadIdx.x;  // 256
  __shared__ __align__(16) unsigned Ah[64 * 132];
  __shared__ __align__(16) unsigned Bh[128 * 132];
  for (int idx = tid; idx < 64 * 128; idx += 256) {
    const int r = idx >> 7, kp = idx & 127;
    const float* s = HH + ((size_t)(i * 64 + r)) * 256 + 2 * kp;
    Ah[r * 132 + kp] = pack2(s[0], s[1]);
  }
  for (int idx = tid; idx < 128 * 128; idx += 256) {
    const int o = idx >> 7, kp = idx & 127;
    Bh[o * 132 + kp] = wlh_h2[o * 128 + kp];
  }
  __syncthreads();
  const int ry = tid >> 4, px = tid & 15;
  float acc[4][8];
#pragma unroll
  for (int k = 0; k < 4; k++)
#pragma unroll
    for (int j = 0; j < 8; j++) acc[k][j] = 0.f;
  for (int kb = 0; kb < 32; kb++) {
    uint4 a4[4], b4[8];
#pragma unroll
    for (int k = 0; k < 4; k++) a4[k] = *(const uint4*)&Ah[(16 * k + ry) * 132 + 4 * kb];
#pragma unroll
    for (int j = 0; j < 8; j++) b4[j] = *(const uint4*)&Bh[(16 * j + px) * 132 + 4 * kb];
#pragma unroll
    for (int k = 0; k < 4; k++)
#pragma unroll
      for (int j = 0; j < 8; j++) {
        acc[k][j] = dot2(a4[k].x, b4[j].x, acc[k][j]);
        acc[k][j] = dot2(a4[k].y, b4[j].y, acc[k][j]);
        acc[k][j] = dot2(a4[k].z, b4[j].z, acc[k][j]);
        acc[k][j] = dot2(a4[k].w, b4[j].w, acc[k][j]);
      }
  }
#pragma unroll
  for (int k = 0; k < 4; k++)
#pragma unroll
    for (int j = 0; j < 8; j++)
      Hl[(i * 64 + 16 * k + ry) * 128 + 16 * j + px] = acc[k][j] + blh[16 * j + px];
}

// Fused Vp GEMM + z. Rows = flattened (b,g) within frame i (2304 rows, tiles
// of 128). z[b,g] = sum_p w[p]*tanh(Hl[b,p] + Vp[b,g,p]).
__global__ void k_att_z(const float* __restrict__ cnn,
                        const unsigned* __restrict__ wcn_h2,
                        const float* __restrict__ bcn,
                        const float* __restrict__ Hl,
                        const float* __restrict__ wwt,
                        float* __restrict__ zbuf) {
  const int bid = blockIdx.x;  // 576 = 32 frames * 18 row tiles
  const int i = bid / 18, rt = bid - 18 * i;
  const int tid = threadIdx.x;  // 256
  const int r0 = rt * 128;
  __shared__ __align__(16) unsigned As[128 * 132];
  __shared__ __align__(16) unsigned Bs[128 * 132];
  __shared__ float zpart[128 * 16];
  __shared__ float Hls[5 * 128];
  __shared__ float wws[128];
  __shared__ float bcs[128];

  for (int idx = tid; idx < 128 * 128; idx += 256) {
    const int r = idx >> 7, kp = idx & 127;
    const int R = r0 + r;
    const int b = R / 36, g = R - b * 36;
    const float* src = cnn + (((size_t)b * 32 + i) * 36 + g) * 256 + 2 * kp;
    As[r * 132 + kp] = pack2(src[0], src[1]);
  }
  for (int idx = tid; idx < 128 * 128; idx += 256) {
    const int o = idx >> 7, kp = idx & 127;
    Bs[o * 132 + kp] = wcn_h2[o * 128 + kp];
  }
  const int bmin = r0 / 36;
  for (int idx = tid; idx < 5 * 128; idx += 256) {
    const int bb = bmin + (idx >> 7);
    if (bb < 64) Hls[idx] = Hl[(i * 64 + bb) * 128 + (idx & 127)];
  }
  if (tid < 128) {
    wws[tid] = wwt[tid];
    bcs[tid] = bcn[tid];
  }
  __syncthreads();

  const int ry = tid >> 4, px = tid & 15;
  float acc[8][8];
#pragma unroll
  for (int k = 0; k < 8; k++)
#pragma unroll
    for (int j = 0; j < 8; j++) acc[k][j] = bcs[16 * j + px];
  for (int kb = 0; kb < 32; kb++) {
    uint4 a4[8], b4[8];
#pragma unroll
    for (int k = 0; k < 8; k++) a4[k] = *(const uint4*)&As[(16 * k + ry) * 132 + 4 * kb];
#pragma unroll
    for (int j = 0; j < 8; j++) b4[j] = *(const uint4*)&Bs[(16 * j + px) * 132 + 4 * kb];
#pragma unroll
    for (int k = 0; k < 8; k++)
#pragma unroll
      for (int j = 0; j < 8; j++) {
        acc[k][j] = dot2(a4[k].x, b4[j].x, acc[k][j]);
        acc[k][j] = dot2(a4[k].y, b4[j].y, acc[k][j]);
        acc[k][j] = dot2(a4[k].z, b4[j].z, acc[k][j]);
        acc[k][j] = dot2(a4[k].w, b4[j].w, acc[k][j]);
      }
  }
#pragma unroll
  for (int k = 0; k < 8; k++) {
    const int r = 16 * k + ry;
    const int R = r0 + r;
    const int b = R / 36;
    const float* HlRow = &Hls[(b - bmin) * 128];
    float zp = 0.f;
#pragma unroll
    for (int j = 0; j < 8; j++) {
      const int po = 16 * j + px;
      zp += wws[po] * tanh_f(HlRow[po] + acc[k][j]);
    }
    zpart[r * 16 + px] = zp;
  }
  __syncthreads();
  if (tid < 128) {
    float z = 0.f;
#pragma unroll
    for (int x = 0; x < 16; x++) z += zpart[tid * 16 + x];
    const int R = r0 + tid;
    const int b = R / 36, g = R - b * 36;
    zbuf[(i * 64 + b) * 36 + g] = z;
  }
}

// Scrambled softmax + weighted V sum; builds fc = [spatial_feat | h_next].
__global__ void k_att_sf(const float* __restrict__ cnn,
                         const float* __restrict__ zbuf,
                         const float* __restrict__ HH,
                         float* __restrict__ fc) {
  const int bid = blockIdx.x;  // 2048 = i*64 + b
  const int i = bid >> 6, b = bid & 63;
  const int tid = threadIdx.x;  // 256
  __shared__ float zl[36];
  __shared__ float el[40];
  __shared__ float red[1];
  if (tid < 36) {
    const int idx = b * 36 + tid;  // scramble: z.T.reshape(64,36)
    zl[tid] = zbuf[(i * 64 + (idx & 63)) * 36 + (idx >> 6)];
  }
  __syncthreads();
  if (tid == 0) {
    float m = zl[0];
    for (int g = 1; g < 36; g++) m = fmaxf(m, zl[g]);
    float s = 0.f;
    for (int g = 0; g < 36; g++) {
      const float e = __expf(zl[g] - m);
      el[g] = e;
      s += e;
    }
    red[0] = 1.f / s;
  }
  __syncthreads();
  const float inv = red[0];
  float accv = 0.f;
  const float* Vb = cnn + (((size_t)b * 32 + i) * 36) * 256 + tid;
#pragma unroll 4
  for (int g = 0; g < 36; g++) accv += el[g] * Vb[g * 256];
  fc[(size_t)bid * 512 + tid] = accv * inv;
  fc[(size_t)bid * 512 + 256 + tid] = HH[((i + 1) * 64 + b) * 256 + tid];
}

// MLP layers 1/2: (2048,512)@(512,512)+b, output packed f16 pairs.
template <int SRCMODE>  // 0: f32 src (fc), 1: packed-h2 src
__global__ void k_mlp(const void* __restrict__ src,
                      const unsigned* __restrict__ wh2,
                      const float* __restrict__ bias,
                      unsigned* __restrict__ dst) {
  const int bid = blockIdx.x;  // 128 = 32 n-tiles * 4 o-tiles
  const int nb = bid >> 2, ob = bid & 3;
  const int n0 = nb * 64, o0 = ob * 128;
  const int tid = threadIdx.x;
  __shared__ __align__(16) unsigned As[64 * 132];
  __shared__ __align__(16) unsigned Bs[128 * 132];
  const int ry = tid >> 4, px = tid & 15;
  float acc[4][8];
#pragma unroll
  for (int k = 0; k < 4; k++)
#pragma unroll
    for (int m = 0; m < 8; m++)
      acc[k][m] = bias[o0 + 32 * (m >> 1) + 2 * px + (m & 1)];
  for (int kc = 0; kc < 2; kc++) {
    __syncthreads();
    for (int idx = tid; idx < 64 * 128; idx += 256) {
      const int r = idx >> 7, kp = idx & 127;
      if (SRCMODE == 0) {
        const float* s = (const float*)src + ((size_t)(n0 + r)) * 512 + kc * 256 + 2 * kp;
        As[r * 132 + kp] = pack2(s[0], s[1]);
      } else {
        As[r * 132 + kp] = ((const unsigned*)src)[((size_t)(n0 + r)) * 256 + kc * 128 + kp];
      }
    }
    for (int idx = tid; idx < 128 * 128; idx += 256) {
      const int o = idx >> 7, kp = idx & 127;
      Bs[o * 132 + kp] = wh2[((size_t)(o0 + o)) * 256 + kc * 128 + kp];
    }
    __syncthreads();
    for (int kb = 0; kb < 32; kb++) {
      uint4 a4[4], b4[8];
#pragma unroll
      for (int k = 0; k < 4; k++)
        a4[k] = *(const uint4*)&As[(16 * k + ry) * 132 + 4 * kb];
#pragma unroll
      for (int m = 0; m < 8; m++)
        b4[m] = *(const uint4*)&Bs[(32 * (m >> 1) + 2 * px + (m & 1)) * 132 + 4 * kb];
#pragma unroll
      for (int k = 0; k < 4; k++)
#pragma unroll
        for (int m = 0; m < 8; m++) {
          acc[k][m] = dot2(a4[k].x, b4[m].x, acc[k][m]);
          acc[k][m] = dot2(a4[k].y, b4[m].y, acc[k][m]);
          acc[k][m] = dot2(a4[k].z, b4[m].z, acc[k][m]);
          acc[k][m] = dot2(a4[k].w, b4[m].w, acc[k][m]);
        }
    }
  }
#pragma unroll
  for (int k = 0; k < 4; k++) {
    const int n = n0 + 16 * k + ry;
#pragma unroll
    for (int j = 0; j < 4; j++)
      dst[(size_t)n * 256 + (o0 >> 1) + 16 * j + px] =
          pack2(acc[k][2 * j], acc[k][2 * j + 1]);
  }
}

// Final layer: (2048,512) -> 6 classes.
__global__ void k_mlp3(const unsigned* __restrict__ y2h2,
                       const unsigned* __restrict__ wm3h2,
                       const float* __restrict__ bm3,
                       float* __restrict__ out) {
  const int nb = blockIdx.x;  // 32
  const int tid = threadIdx.x;
  __shared__ __align__(16) unsigned Ys[64 * 256];
  __shared__ __align__(16) unsigned Ws[6 * 256];
  for (int idx = tid; idx < 64 * 256; idx += 256)
    Ys[idx] = y2h2[(size_t)nb * 64 * 256 + idx];
  for (int idx = tid; idx < 6 * 256; idx += 256) Ws[idx] = wm3h2[idx];
  __syncthreads();
  for (int u = 0; u < 2; u++) {
    const int idx = tid + u * 256;
    if (idx < 384) {
      const int nl = idx / 6, c = idx - 6 * nl;
      float a0 = 0.f, a1 = 0.f;
#pragma unroll
      for (int kq = 0; kq < 64; kq++) {
        const uint4 y4 = *(const uint4*)&Ys[nl * 256 + 4 * kq];
        const uint4 w4 = *(const uint4*)&Ws[c * 256 + 4 * kq];
        a0 = dot2(y4.x, w4.x, a0);
        a1 = dot2(y4.y, w4.y, a1);
        a0 = dot2(y4.z, w4.z, a0);
        a1 = dot2(y4.w, w4.w, a1);
      }
      out[(size_t)(nb * 64 + nl) * 6 + c] = a0 + a1 + bm3[c];
    }
  }
}

// ---------------------------------------------------------------------------
extern "C" void kernel_launch(void* const* d_in, const int* in_sizes, int n_in,
                              void* d_out, int out_size, void* d_ws,
                              size_t ws_size, hipStream_t stream) {
  (void)in_sizes; (void)n_in; (void)out_size; (void)ws_size;
  const float* cnn  = (const float*)d_in[0];
  const float* gaze = (const float*)d_in[1];
  const float* W_lh = (const float*)d_in[2];
  const float* b_lh = (const float*)d_in[3];
  const float* W_cn = (const float*)d_in[4];
  const float* b_cn = (const float*)d_in[5];
  const float* w_wt = (const float*)d_in[6];
  const float* Wih  = (const float*)d_in[7];
  const float* Whh  = (const float*)d_in[8];
  const float* bih  = (const float*)d_in[9];
  const float* bhh  = (const float*)d_in[10];
  const float* Wh1  = (const float*)d_in[11];
  const float* bh1  = (const float*)d_in[12];
  const float* Wh2  = (const float*)d_in[13];
  const float* bh2  = (const float*)d_in[14];
  const float* Wc1  = (const float*)d_in[15];
  const float* bc1  = (const float*)d_in[16];
  const float* Wc2  = (const float*)d_in[17];
  const float* bc2  = (const float*)d_in[18];
  const float* Wm1  = (const float*)d_in[19];
  const float* bm1  = (const float*)d_in[20];
  const float* Wm2  = (const float*)d_in[21];
  const float* bm2  = (const float*)d_in[22];
  const float* Wm3  = (const float*)d_in[23];
  const float* bm3  = (const float*)d_in[24];
  float* out = (float*)d_out;

  unsigned* W = (unsigned*)d_ws;
  float* Wf = (float*)d_ws;
  // workspace offsets in dwords
  const size_t O_xg  = 0;                    // [31][64][1024] f32
  const size_t O_wv  = 2031616;              // [24][1024] uint4 = 98304 u32
  const size_t O_wl  = O_wv + 98304;         // [1024][32]     u32
  const size_t O_HH  = O_wl + 32768;         // [33][64][256]  f32
  const size_t O_c0  = O_HH + 540672;        // [64][256]      f32
  const size_t O_Hl  = O_c0 + 16384;         // [32][64][128]  f32
  const size_t O_z   = O_Hl + 262144;        // [32][64][36]   f32
  const size_t O_fc  = O_z + 73728;          // [2048][512]    f32
  const size_t O_y1  = O_fc + 1048576;       // [2048][256]    u32 (h2)
  const size_t O_y2  = O_y1 + 524288;        // [2048][256]    u32 (h2)
  const size_t O_wcn = O_y2 + 524288;        // [128][128]     u32
  const size_t O_wlh = O_wcn + 16384;
  const size_t O_wm1 = O_wlh + 16384;        // [512][256]
  const size_t O_wm2 = O_wm1 + 131072;
  const size_t O_wm3 = O_wm2 + 131072;       // [6][256]

  float* xg  = Wf + O_xg;
  float* HH  = Wf + O_HH;
  float* c0f = Wf + O_c0;
  float* Hlf = Wf + O_Hl;
  float* zf  = Wf + O_z;
  float* fcf = Wf + O_fc;

  // --- prepacking (independent) ---
  k_pack_wv<<<512, 256, 0, stream>>>(Whh, W + O_wv, W + O_wl);
  k_packh2<<<64, 256, 0, stream>>>(W_cn, W + O_wcn, 16384);
  k_packh2<<<64, 256, 0, stream>>>(W_lh, W + O_wlh, 16384);
  k_packh2<<<512, 256, 0, stream>>>(Wm1, W + O_wm1, 131072);
  k_packh2<<<512, 256, 0, stream>>>(Wm2, W + O_wm2, 131072);
  k_packh2<<<6, 256, 0, stream>>>(Wm3, W + O_wm3, 1536);
  k_xg<<<7936, 256, 0, stream>>>(gaze, Wih, bih, bhh, xg);
  k_init<<<64, 256, 0, stream>>>(gaze, Wh1, bh1, Wh2, bh2, Wc1, bc1, Wc2, bc2,
                                 HH, c0f);
  // --- the sequential chain ---
  k_lstm<<<64, 1024, 0, stream>>>(xg, W + O_wv, W + O_wl, c0f, HH);
  // --- batched attention ---
  k_hl<<<32, 256, 0, stream>>>(HH, W + O_wlh, b_lh, Hlf);
  k_att_z<<<576, 256, 0, stream>>>(cnn, W + O_wcn, b_cn, Hlf, w_wt, zf);
  k_att_sf<<<2048, 256, 0, stream>>>(cnn, zf, HH, fcf);
  // --- batched MLP ---
  k_mlp<0><<<128, 256, 0, stream>>>((const void*)fcf, W + O_wm1, bm1, W + O_y1);
  k_mlp<1><<<128, 256, 0, stream>>>((const void*)(W + O_y1), W + O_wm2, bm2, W + O_y2);
  k_mlp3<<<32, 256, 0, stream>>>(W + O_y2, W + O_wm3, bm3, out);
}